// Round 9
// baseline (678.510 us; speedup 1.0000x reference)
//
#include <hip/hip_runtime.h>
#include <math.h>

// Problem constants (match reference)
constexpr int Bc = 2, Kc = 384, Nc = 4096, Dc = 1024;
constexpr int Hc = 150, Lc = 12, DDc = 20, NBc = 10;
constexpr int Mrows = Bc * Kc; // 768

typedef __attribute__((ext_vector_type(8))) unsigned short ushort8;
typedef __attribute__((ext_vector_type(8))) short short8;
typedef __attribute__((ext_vector_type(4))) float f32x4;

__device__ __forceinline__ float sigmoidf_(float x) { return 1.0f / (1.0f + expf(-x)); }

// f32 -> bf16 (RNE)
__device__ __forceinline__ unsigned short f2b(float f) {
    unsigned u = __float_as_uint(f);
    unsigned r = (u + 0x7fffu + ((u >> 16) & 1u)) >> 16;
    return (unsigned short)r;
}

__global__ __launch_bounds__(256) void cvt_k(const float* __restrict__ s,
                                             unsigned short* __restrict__ d, int n) {
    for (int i = blockIdx.x * 256 + threadIdx.x; i < n; i += gridDim.x * 256)
        d[i] = f2b(s[i]);
}

// dist table: dtab[n][h] = dist_emb[n] @ Wd + bd   (10x150, f32)
__global__ __launch_bounds__(256) void dtab_k(const float* __restrict__ de,
                                              const float* __restrict__ Wd,
                                              const float* __restrict__ bd,
                                              float* __restrict__ dtab) {
    int idx = blockIdx.x * 256 + threadIdx.x;
    if (idx >= NBc * Hc) return;
    int n = idx / Hc, h = idx - n * Hc;
    float s = bd[h];
#pragma unroll
    for (int k = 0; k < DDc; ++k) s = fmaf(de[n * DDc + k], Wd[k * Hc + h], s);
    dtab[n * Hc + h] = s;
}

// f32 W[K][N] -> bf16 WT[N][K]  (tiled transpose-convert; K,N multiples of 32)
__global__ __launch_bounds__(256) void trw_k(const float* __restrict__ Wsrc,
                                             unsigned short* __restrict__ WT,
                                             int K, int N) {
    __shared__ unsigned short t[32][33];
    const int k0 = blockIdx.y * 32, n0 = blockIdx.x * 32;
    const int tx = threadIdx.x & 31, ty = threadIdx.x >> 5; // ty 0..7
#pragma unroll
    for (int i = 0; i < 4; ++i)
        t[ty + i * 8][tx] = f2b(Wsrc[(size_t)(k0 + ty + i * 8) * N + n0 + tx]);
    __syncthreads();
#pragma unroll
    for (int i = 0; i < 4; ++i)
        WT[(size_t)(n0 + ty + i * 8) * K + k0 + tx] = t[tx][ty + i * 8];
}

// WlrT[r][k] = bf16((r<150?Wl:Wr)[k][r%150]); blr = [bl|br]
__global__ __launch_bounds__(256) void trwlr_k(const float* __restrict__ Wl,
                                               const float* __restrict__ Wr,
                                               const float* __restrict__ bl,
                                               const float* __restrict__ br,
                                               unsigned short* __restrict__ WlrT,
                                               float* __restrict__ blr) {
    int idx = blockIdx.x * 256 + threadIdx.x;
    if (idx < Hc) { blr[idx] = bl[idx]; blr[Hc + idx] = br[idx]; }
    if (idx >= 2 * Hc * Dc) return;
    int r = idx >> 10, k = idx & 1023;
    float v = (r < Hc) ? Wl[(size_t)k * Hc + r] : Wr[(size_t)k * Hc + (r - Hc)];
    WlrT[idx] = f2b(v);
}

// bf16 tile transpose: dst[z][C][R] = src[z][R][C]^T  (R,C multiples of 32)
__global__ __launch_bounds__(256) void trb_k(const unsigned short* __restrict__ src,
                                             unsigned short* __restrict__ dst,
                                             int R, int C, long sBatch, long dBatch) {
    __shared__ unsigned short t[32][33];
    const int z = blockIdx.z;
    src += (size_t)z * sBatch;
    dst += (size_t)z * dBatch;
    const int r0 = blockIdx.y * 32, c0 = blockIdx.x * 32;
    const int tx = threadIdx.x & 31, ty = threadIdx.x >> 5;
#pragma unroll
    for (int i = 0; i < 4; ++i)
        t[ty + i * 8][tx] = src[(size_t)(r0 + ty + i * 8) * C + c0 + tx];
    __syncthreads();
#pragma unroll
    for (int i = 0; i < 4; ++i)
        dst[(size_t)(c0 + ty + i * 8) * R + r0 + tx] = t[tx][ty + i * 8];
}

// ---------------------------------------------------------------------------
// mfma2: wave-split-K MFMA GEMM. Block = 4 waves on ONE 32x32 output tile.
// Wave w accumulates k in [w*Kd/4, (w+1)*Kd/4) with a PRIVATE LDS slice
// (no barriers in the K-loop; intra-wave LDS RAW is in-order). Wave tile =
// 2x2 16x16 frags -> 4 MFMA per 4 ds_read_b128. Final cross-wave reduce in LDS.
// A: NSRC bf16 sources ([rows][1024] each when NSRC>1); WT: bf16 [N][Kd].
// z-batching: a0 += z*aBatch, WT += (z&wmask)*wBatch, rs += z*rsBatch,
// outf/outb += z*oBatch.
// EPI: 0 outf=v+bias[col]; 1 outb=bf16(tanh v); 2 outf=v,outb=bf16(v);
//      3 g=sig(v+bias[col]), r=g*E1+(1-g)*E2, outf=r,outb=bf16(r);
//      4 outb=bf16(v*rs[row])
// Kd must be divisible by 128. C/D layout: row=(lane>>4)*4+reg, col=lane&15.
// ---------------------------------------------------------------------------
template <int NSRC, int EPI>
__global__ __launch_bounds__(256) void mfma2(
    const unsigned short* __restrict__ a0, const unsigned short* __restrict__ a1,
    const unsigned short* __restrict__ a2, int arstride, long aBatch,
    const unsigned short* __restrict__ WT, long wBatch, int wmask,
    int N, int Kd,
    const float* __restrict__ bias, const float* __restrict__ rs, long rsBatch,
    const float* __restrict__ E1, const float* __restrict__ E2,
    float* __restrict__ outf, unsigned short* __restrict__ outb, long oBatch) {
    constexpr int LDA = 36;                       // shorts; 72B rows: spread banks
    __shared__ unsigned short smem[4 * 2 * 32 * LDA]; // 18432 B; reused as f32 red
    float* red = (float*)smem;                    // [4][32][33] = 16896 B

    const int z = blockIdx.z;
    a0 += (size_t)z * aBatch;
    WT += (size_t)(z & wmask) * wBatch;
    if (rs) rs += (size_t)z * rsBatch;
    if (outb) outb += (size_t)z * oBatch;
    if (outf) outf += (size_t)z * oBatch;

    const int tid = threadIdx.x;
    const int wave = tid >> 6, lane = tid & 63;
    const int l15 = lane & 15, lg = lane >> 4;
    const int row0 = blockIdx.y * 32, col0 = blockIdx.x * 32;

    unsigned short* Aw = smem + wave * (2 * 32 * LDA);
    unsigned short* Bw = Aw + 32 * LDA;

    const int srow = lane >> 1;          // 0..31
    const int soct = (lane & 1) * 16;    // 0 or 16 (shorts)

    const int chunk = Kd >> 2;
    const int kbeg = wave * chunk;
    f32x4 acc[2][2] = {};

    for (int k0 = kbeg; k0 < kbeg + chunk; k0 += 32) {
        // stage A slice [32 rows][32 k] (vectorized, own wave's region)
        {
            int kglob = k0 + soct;
            const unsigned short* asrc = a0;
            int kl = kglob;
            if (NSRC > 1) {
                int s = kglob >> 10;
                kl = kglob & 1023;
                asrc = (s == 0) ? a0 : ((s == 1 || NSRC == 2) ? a1 : a2);
            }
            const unsigned short* p = asrc + (size_t)(row0 + srow) * arstride + kl;
            *reinterpret_cast<ushort8*>(&Aw[srow * LDA + soct]) =
                *reinterpret_cast<const ushort8*>(p);
            *reinterpret_cast<ushort8*>(&Aw[srow * LDA + soct + 8]) =
                *reinterpret_cast<const ushort8*>(p + 8);
        }
        // stage B slice from WT[col][k] (vectorized row-major read)
        {
            int col = col0 + srow;
            if (col < N) {
                const unsigned short* p = WT + (size_t)col * Kd + k0 + soct;
                *reinterpret_cast<ushort8*>(&Bw[srow * LDA + soct]) =
                    *reinterpret_cast<const ushort8*>(p);
                *reinterpret_cast<ushort8*>(&Bw[srow * LDA + soct + 8]) =
                    *reinterpret_cast<const ushort8*>(p + 8);
            } else {
                ushort8 z8 = {};
                *reinterpret_cast<ushort8*>(&Bw[srow * LDA + soct]) = z8;
                *reinterpret_cast<ushort8*>(&Bw[srow * LDA + soct + 8]) = z8;
            }
        }
        // frags + 4 MFMA (intra-wave LDS: in-order, no barrier)
        short8 af0 = *reinterpret_cast<const short8*>(&Aw[(l15)*LDA + lg * 8]);
        short8 af1 = *reinterpret_cast<const short8*>(&Aw[(16 + l15) * LDA + lg * 8]);
        short8 bf0 = *reinterpret_cast<const short8*>(&Bw[(l15)*LDA + lg * 8]);
        short8 bf1 = *reinterpret_cast<const short8*>(&Bw[(16 + l15) * LDA + lg * 8]);
        acc[0][0] = __builtin_amdgcn_mfma_f32_16x16x32_bf16(af0, bf0, acc[0][0], 0, 0, 0);
        acc[0][1] = __builtin_amdgcn_mfma_f32_16x16x32_bf16(af0, bf1, acc[0][1], 0, 0, 0);
        acc[1][0] = __builtin_amdgcn_mfma_f32_16x16x32_bf16(af1, bf0, acc[1][0], 0, 0, 0);
        acc[1][1] = __builtin_amdgcn_mfma_f32_16x16x32_bf16(af1, bf1, acc[1][1], 0, 0, 0);
    }

    __syncthreads(); // all waves done with staging slices; reuse smem as red
#pragma unroll
    for (int m = 0; m < 2; ++m)
#pragma unroll
        for (int n = 0; n < 2; ++n)
#pragma unroll
            for (int r = 0; r < 4; ++r)
                red[wave * 1056 + (m * 16 + lg * 4 + r) * 33 + (n * 16 + l15)] = acc[m][n][r];
    __syncthreads();

#pragma unroll
    for (int p = 0; p < 4; ++p) {
        int idx = tid + p * 256;
        int row = idx >> 5, col = idx & 31;
        int gcol = col0 + col;
        if (gcol >= N) continue;
        float v = red[row * 33 + col] + red[1056 + row * 33 + col] +
                  red[2112 + row * 33 + col] + red[3168 + row * 33 + col];
        int grow = row0 + row;
        size_t ix = (size_t)grow * N + gcol;
        if (EPI == 0) {
            outf[ix] = v + bias[gcol];
        } else if (EPI == 1) {
            outb[ix] = f2b(tanhf(v));
        } else if (EPI == 2) {
            outf[ix] = v;
            outb[ix] = f2b(v);
        } else if (EPI == 3) {
            float g = sigmoidf_(v + bias[gcol]);
            float rv = g * E1[ix] + (1.0f - g) * E2[ix];
            outf[ix] = rv;
            outb[ix] = f2b(rv);
        } else if (EPI == 4) {
            outb[ix] = f2b(v * rs[grow]);
        }
    }
}

// ---------------------------------------------------------------------------
// Scorer: scores[b,i,j,:] (+)= relu(l[b,i,:] + r[b,j,:] + dtab[bucket]) @ Wo + bo
// Lm/Rm row stride lst (packed [l|r]).
// ---------------------------------------------------------------------------
template <bool ADD>
__global__ __launch_bounds__(256) void scorer_k(const float* __restrict__ Lm,
                                                const float* __restrict__ Rm,
                                                int lst,
                                                const float* __restrict__ dtab,
                                                const int* __restrict__ sb,
                                                const int* __restrict__ se,
                                                const float* __restrict__ Wo,
                                                const float* __restrict__ bo,
                                                float* __restrict__ scores) {
    const int b = blockIdx.z;
    const int i0 = blockIdx.y * 16;
    const int j0 = blockIdx.x * 16;
    __shared__ float Ll[16 * 151];
    __shared__ float Rl[16 * 151];
    __shared__ float Dl[NBc * 151];
    __shared__ float Wol[Hc * Lc];
    __shared__ float bol[Lc];
    const int tid = threadIdx.x;
    for (int idx = tid; idx < 16 * Hc; idx += 256) {
        int r = idx / Hc, c = idx - r * Hc;
        Ll[r * 151 + c] = Lm[(size_t)(b * Kc + i0 + r) * lst + c];
        Rl[r * 151 + c] = Rm[(size_t)(b * Kc + j0 + r) * lst + c];
    }
    for (int idx = tid; idx < NBc * Hc; idx += 256) {
        int r = idx / Hc, c = idx - r * Hc;
        Dl[r * 151 + c] = dtab[r * Hc + c];
    }
    for (int idx = tid; idx < Hc * Lc; idx += 256) Wol[idx] = Wo[idx];
    if (tid < Lc) bol[tid] = bo[tid];
    __syncthreads();

    const int ty = tid >> 4, tx = tid & 15;
    const int i = i0 + ty, j = j0 + tx;
    int d = sb[b * Kc + j] - se[b * Kc + i];
    int da = d < 0 ? -d : d;
    int bucket = (da <= 4) ? da : min(31 - __clz(da) + 3, NBc - 1);
    const float* lp = &Ll[ty * 151];
    const float* rp = &Rl[tx * 151];
    const float* dp = &Dl[bucket * 151];
    float acc[Lc] = {};
    for (int h = 0; h < Hc; ++h) {
        float v = lp[h] + rp[h] + dp[h];
        v = fmaxf(v, 0.0f);
#pragma unroll
        for (int l = 0; l < Lc; ++l) acc[l] = fmaf(v, Wol[h * Lc + l], acc[l]);
    }
    size_t base = (((size_t)(b * Kc + i)) * Kc + j) * Lc;
#pragma unroll
    for (int l = 0; l < Lc; ++l) {
        float v = acc[l] + bol[l];
        if (ADD) v += scores[base + l];
        scores[base + l] = v;
    }
}

// probs -> PRf (f32), PRbf (bf16). (transpose of P done by trb_k)
__global__ __launch_bounds__(256) void probs_k(const float* __restrict__ scores,
                                               const float* __restrict__ mask,
                                               float* __restrict__ PRf,
                                               unsigned short* __restrict__ PRbf) {
    int idx = blockIdx.x * 256 + threadIdx.x;
    if (idx >= Bc * Kc * Kc) return;
    const float* s = scores + (size_t)idx * Lc;
    float m = s[0];
#pragma unroll
    for (int l = 1; l < Lc; ++l) m = fmaxf(m, s[l]);
    float p = sigmoidf_(m) * mask[idx];
    PRf[idx] = p;
    PRbf[idx] = f2b(p);
}

// rowsum: s1inv[row] = 1/(sum_j PRf[row][j] + 1e-7)
__global__ __launch_bounds__(256) void rowsum_k(const float* __restrict__ probs,
                                                float* __restrict__ s1inv) {
    int row = (blockIdx.x * 256 + threadIdx.x) >> 6;
    int lane = threadIdx.x & 63;
    if (row >= Mrows) return;
    const float* p = probs + (size_t)row * Kc;
    float s = 0.0f;
    for (int j = lane; j < Kc; j += 64) s += p[j];
#pragma unroll
    for (int off = 32; off > 0; off >>= 1) s += __shfl_down(s, off);
    if (lane == 0) s1inv[row] = 1.0f / (s + 1e-7f);
}

// colsum: s2inv[b*K+j] = 1/(sum_i PRf[b][i][j] + 1e-7)
__global__ __launch_bounds__(256) void colsum_k(const float* __restrict__ probs,
                                                float* __restrict__ s2inv) {
    int idx = blockIdx.x * 256 + threadIdx.x;
    if (idx >= Mrows) return;
    int b = idx / Kc, j = idx - b * Kc;
    const float* p = probs + (size_t)b * Kc * Kc + j;
    float s = 0.0f;
    for (int i = 0; i < Kc; ++i) s += p[(size_t)i * Kc];
    s2inv[idx] = 1.0f / (s + 1e-7f);
}

__global__ __launch_bounds__(256) void copy4_k(const float4* __restrict__ s,
                                               float4* __restrict__ d, int n4) {
    int i = blockIdx.x * 256 + threadIdx.x;
    if (i < n4) d[i] = s[i];
}

// scatter: numpy sequential-set semantics
__global__ __launch_bounds__(256) void scatter_k(const float* __restrict__ Uf,
                                                 const int* __restrict__ pidx,
                                                 const int* __restrict__ slen,
                                                 float* __restrict__ out_all) {
    int bk = blockIdx.x;
    int b = bk / Kc, k = bk - b * Kc;
    if (k >= slen[b]) return;
    int idx = pidx[bk];
    if (k + 1 < Kc && pidx[bk + 1] == idx) return;
    const float4* s = (const float4*)(Uf + (size_t)bk * Dc);
    float4* d = (float4*)(out_all + ((size_t)b * Nc + idx) * Dc);
    for (int c = threadIdx.x; c < Dc / 4; c += 256) d[c] = s[c];
}

// ---------------------------------------------------------------------------
extern "C" void kernel_launch(void* const* d_in, const int* in_sizes, int n_in,
                              void* d_out, int out_size, void* d_ws, size_t ws_size,
                              hipStream_t stream) {
    const float* span_vecs = (const float*)d_in[0];
    const float* all_span_vecs = (const float*)d_in[1];
    const int* span_begin = (const int*)d_in[2];
    const int* span_end = (const int*)d_in[3];
    const float* square_mask = (const float*)d_in[4];
    const int* prune_indices = (const int*)d_in[5];
    const int* span_lengths = (const int*)d_in[6];
    const float* Wl = (const float*)d_in[8];
    const float* bl = (const float*)d_in[9];
    const float* Wr = (const float*)d_in[10];
    const float* br = (const float*)d_in[11];
    const float* dist_emb = (const float*)d_in[12];
    const float* Wd = (const float*)d_in[13];
    const float* bd = (const float*)d_in[14];
    const float* Wo = (const float*)d_in[15];
    const float* bo = (const float*)d_in[16];
    const float* Wff1 = (const float*)d_in[17];
    const float* Wff2 = (const float*)d_in[18];
    const float* Wg = (const float*)d_in[19];
    const float* bg = (const float*)d_in[20];

    float* out_all = (float*)d_out;                    // B*N*D = 8,388,608 floats
    float* out_u = out_all + (size_t)Bc * Nc * Dc;     // B*K*D
    float* out_sc = out_u + (size_t)Mrows * Dc;        // B*K*K*L

    // Scratch inside out_all (dead until final copy); float-slot offsets.
    // Adjacency required: PT = PRbf + 2*KK sh; C2bf = C1bf + 2*KD sh; S1S2 [4][384].
    float* w = out_all;
    float* DT = w;                                          // 1,600
    float* PRf = w + 1600;                                  // 147,456
    float* S1 = w + 149056;                                 // [4][384] = 1,536
    float* CT = w + 150592;                                 // 786,432
    float* UA = w + 937024;                                 // 786,432
    float* LRM = w + 1723456;                               // 230,400
    unsigned short* UbfA = (unsigned short*)(w + 1953856);  // 786,432 sh
    unsigned short* UbfB = (unsigned short*)(w + 2347072);  // 786,432 sh
    unsigned short* C1bf = (unsigned short*)(w + 2740288);  // [4][393216] sh (C1 b0,b1 | C2 b0,b1)
    unsigned short* C2bf = C1bf + 2 * (size_t)Kc * Dc;
    unsigned short* T1bf = (unsigned short*)(w + 3526720);  // 786,432 sh
    unsigned short* PRbf = (unsigned short*)(w + 3919936);  // [4][147456] sh (P b0,b1 | PT b0,b1)
    unsigned short* PT = PRbf + 2 * (size_t)Kc * Kc;
    unsigned short* UT = (unsigned short*)(w + 4214848);    // [2][1024][384] sh = 786,432 sh
    unsigned short* Wff1T = (unsigned short*)(w + 4608064); // 3,145,728 sh
    unsigned short* Wff2T = (unsigned short*)(w + 6180928); // 1,048,576 sh
    unsigned short* WgT = (unsigned short*)(w + 6705216);   // 2,097,152 sh
    unsigned short* WlrT = (unsigned short*)(w + 7753792);  // 307,200 sh
    float* blr = w + 7907392;                               // 320 -> ends 7,907,712
    unsigned short* CTbf = C1bf; // alias: C1bf dead after FF1 consumes it
    float* UB = out_u;           // final u lands in place

    const long KK = (long)Kc * Kc;   // 147,456
    const long KD = (long)Kc * Dc;   // 393,216

    dim3 blk(256);
    dim3 g_sc(Kc / 16, Kc / 16, Bc);
    dim3 g_d(32, 24, 1);    // 32x32 tiles: N=1024, M=768
    dim3 g_lr(10, 24, 1);   // N=300 (guarded)
    dim3 g_pu(32, 12, 4);   // per-z M=384; z = {P b0, P b1, PT b0, PT b1}
    dim3 g_tru(32, 12, 2);  // U transpose: R=384, C=1024 per batch
    dim3 g_trp(12, 12, 2);  // P transpose: 384x384 per batch

    // one-time conversions / transposes
    cvt_k<<<2048, blk, 0, stream>>>(span_vecs, UbfA, Mrows * Dc);
    trb_k<<<g_tru, blk, 0, stream>>>(UbfA, UT, Kc, Dc, KD, KD);
    trw_k<<<dim3(32, 96), blk, 0, stream>>>(Wff1, Wff1T, 3 * Dc, Dc);
    trw_k<<<dim3(32, 32), blk, 0, stream>>>(Wff2, Wff2T, Dc, Dc);
    trw_k<<<dim3(32, 64), blk, 0, stream>>>(Wg, WgT, 2 * Dc, Dc);
    trwlr_k<<<(2 * Hc * Dc + 255) / 256, blk, 0, stream>>>(Wl, Wr, bl, br, WlrT, blr);
    dtab_k<<<(NBc * Hc + 255) / 256, blk, 0, stream>>>(dist_emb, Wd, bd, DT);

    // initial l|r projection + scorer
    mfma2<1, 0><<<g_lr, blk, 0, stream>>>(UbfA, nullptr, nullptr, Dc, 0, WlrT, 0, 0,
                                          2 * Hc, Dc, blr, nullptr, 0, nullptr, nullptr,
                                          LRM, nullptr, 0);
    scorer_k<false><<<g_sc, blk, 0, stream>>>(LRM, LRM + Hc, 2 * Hc, DT, span_begin, span_end,
                                              Wo, bo, out_sc);

    const float* UcurF = span_vecs;
    unsigned short* Ubf = UbfA;
    float* UnextF_arr[2] = {UA, UB};
    unsigned short* UbfN_arr[2] = {UbfB, UbfA};
    for (int it = 0; it < 2; ++it) {
        float* UnextF = UnextF_arr[it];
        unsigned short* UbfN = UbfN_arr[it];
        probs_k<<<(Bc * Kc * Kc + 255) / 256, blk, 0, stream>>>(out_sc, square_mask, PRf, PRbf);
        rowsum_k<<<Mrows / 4, blk, 0, stream>>>(PRf, S1);
        colsum_k<<<(Mrows + 255) / 256, blk, 0, stream>>>(PRf, S1 + Mrows);
        trb_k<<<g_trp, blk, 0, stream>>>(PRbf, PT, Kc, Kc, KK, KK);
        // fused PU: z -> A=PRbf+z*KK, B=UT+(z&1)*KD, rs=S1+z*384, out=C1bf+z*KD
        mfma2<1, 4><<<g_pu, blk, 0, stream>>>(PRbf, nullptr, nullptr, Kc, KK,
                                              UT, KD, 1, Dc, Kc,
                                              nullptr, S1, Kc, nullptr, nullptr,
                                              nullptr, C1bf, KD);
        // T1 = tanh([U|C1|C2] @ Wff1)
        mfma2<3, 1><<<g_d, blk, 0, stream>>>(Ubf, C1bf, C2bf, Dc, 0, Wff1T, 0, 0,
                                             Dc, 3 * Dc, nullptr, nullptr, 0, nullptr, nullptr,
                                             nullptr, T1bf, 0);
        // CT = T1 @ Wff2 (f32 + bf16)
        mfma2<1, 2><<<g_d, blk, 0, stream>>>(T1bf, nullptr, nullptr, Dc, 0, Wff2T, 0, 0,
                                             Dc, Dc, nullptr, nullptr, 0, nullptr, nullptr,
                                             CT, CTbf, 0);
        // gate
        mfma2<2, 3><<<g_d, blk, 0, stream>>>(Ubf, CTbf, nullptr, Dc, 0, WgT, 0, 0,
                                             Dc, 2 * Dc, bg, nullptr, 0, UcurF, CT,
                                             UnextF, UbfN, 0);
        trb_k<<<g_tru, blk, 0, stream>>>(UbfN, UT, Kc, Dc, KD, KD);
        // next l|r + scorer (residual add)
        mfma2<1, 0><<<g_lr, blk, 0, stream>>>(UbfN, nullptr, nullptr, Dc, 0, WlrT, 0, 0,
                                              2 * Hc, Dc, blr, nullptr, 0, nullptr, nullptr,
                                              LRM, nullptr, 0);
        scorer_k<true><<<g_sc, blk, 0, stream>>>(LRM, LRM + Hc, 2 * Hc, DT, span_begin, span_end,
                                                 Wo, bo, out_sc);
        UcurF = UnextF;
        Ubf = UbfN;
    }

    // final u already in out_u (UB alias). Fill out_all, then scatter.
    copy4_k<<<((Bc * Nc * Dc / 4) + 255) / 256, blk, 0, stream>>>(
        (const float4*)all_span_vecs, (float4*)out_all, Bc * Nc * Dc / 4);
    scatter_k<<<Mrows, blk, 0, stream>>>(out_u, prune_indices, span_lengths, out_all);
}

// Round 10
// 456.016 us; speedup vs baseline: 1.4879x; 1.4879x over previous
//
#include <hip/hip_runtime.h>
#include <math.h>

// Problem constants (match reference)
constexpr int Bc = 2, Kc = 384, Nc = 4096, Dc = 1024;
constexpr int Hc = 150, Lc = 12, DDc = 20, NBc = 10;
constexpr int Mrows = Bc * Kc; // 768

typedef __attribute__((ext_vector_type(8))) unsigned short ushort8;
typedef __attribute__((ext_vector_type(8))) short short8;
typedef __attribute__((ext_vector_type(4))) float f32x4;

__device__ __forceinline__ float sigmoidf_(float x) { return 1.0f / (1.0f + expf(-x)); }

__device__ __forceinline__ unsigned short f2b(float f) {
    unsigned u = __float_as_uint(f);
    unsigned r = (u + 0x7fffu + ((u >> 16) & 1u)) >> 16;
    return (unsigned short)r;
}
__device__ __forceinline__ float b2f(unsigned short u) {
    return __uint_as_float((unsigned)u << 16);
}

__global__ __launch_bounds__(256) void cvt_k(const float* __restrict__ s,
                                             unsigned short* __restrict__ d, int n) {
    for (int i = blockIdx.x * 256 + threadIdx.x; i < n; i += gridDim.x * 256)
        d[i] = f2b(s[i]);
}

// dist table (f32)
__global__ __launch_bounds__(256) void dtab_k(const float* __restrict__ de,
                                              const float* __restrict__ Wd,
                                              const float* __restrict__ bd,
                                              float* __restrict__ dtab) {
    int idx = blockIdx.x * 256 + threadIdx.x;
    if (idx >= NBc * Hc) return;
    int n = idx / Hc, h = idx - n * Hc;
    float s = bd[h];
#pragma unroll
    for (int k = 0; k < DDc; ++k) s = fmaf(de[n * DDc + k], Wd[k * Hc + h], s);
    dtab[n * Hc + h] = s;
}

// f32 W[K][N] -> bf16 WT[N][K]
__global__ __launch_bounds__(256) void trw_k(const float* __restrict__ Wsrc,
                                             unsigned short* __restrict__ WT,
                                             int K, int N) {
    __shared__ unsigned short t[32][33];
    const int k0 = blockIdx.y * 32, n0 = blockIdx.x * 32;
    const int tx = threadIdx.x & 31, ty = threadIdx.x >> 5;
#pragma unroll
    for (int i = 0; i < 4; ++i)
        t[ty + i * 8][tx] = f2b(Wsrc[(size_t)(k0 + ty + i * 8) * N + n0 + tx]);
    __syncthreads();
#pragma unroll
    for (int i = 0; i < 4; ++i)
        WT[(size_t)(n0 + ty + i * 8) * K + k0 + tx] = t[tx][ty + i * 8];
}

// WlrT[r][k] = bf16((r<150?Wl:Wr)[k][r%150]); blr = [bl|br]
__global__ __launch_bounds__(256) void trwlr_k(const float* __restrict__ Wl,
                                               const float* __restrict__ Wr,
                                               const float* __restrict__ bl,
                                               const float* __restrict__ br,
                                               unsigned short* __restrict__ WlrT,
                                               float* __restrict__ blr) {
    int idx = blockIdx.x * 256 + threadIdx.x;
    if (idx < Hc) { blr[idx] = bl[idx]; blr[Hc + idx] = br[idx]; }
    if (idx >= 2 * Hc * Dc) return;
    int r = idx >> 10, k = idx & 1023;
    float v = (r < Hc) ? Wl[(size_t)k * Hc + r] : Wr[(size_t)k * Hc + (r - Hc)];
    WlrT[idx] = f2b(v);
}

// bf16 tile transpose: dst[z][C][R] = src[z][R][C]^T
__global__ __launch_bounds__(256) void trb_k(const unsigned short* __restrict__ src,
                                             unsigned short* __restrict__ dst,
                                             int R, int C, long sBatch, long dBatch) {
    __shared__ unsigned short t[32][33];
    const int z = blockIdx.z;
    src += (size_t)z * sBatch;
    dst += (size_t)z * dBatch;
    const int r0 = blockIdx.y * 32, c0 = blockIdx.x * 32;
    const int tx = threadIdx.x & 31, ty = threadIdx.x >> 5;
#pragma unroll
    for (int i = 0; i < 4; ++i)
        t[ty + i * 8][tx] = src[(size_t)(r0 + ty + i * 8) * C + c0 + tx];
    __syncthreads();
#pragma unroll
    for (int i = 0; i < 4; ++i)
        dst[(size_t)(c0 + ty + i * 8) * R + r0 + tx] = t[tx][ty + i * 8];
}

// ---------------------------------------------------------------------------
// mfma3: 64x64 tile, 4 waves x (2x2 16x16 frags), K-step 64, double-buffered
// LDS with prefetch-to-regs issued BEFORE compute; ONE barrier per K-step.
// A: NSRC bf16 sources ([rows][1024] each when NSRC>1), arstride rows.
// B: !BTRANS -> pre-transposed [N][Kd] (bstride=Kd, b128 stage);
//     BTRANS -> row-major [Kd][N] (bstride=N, transpose-on-write stage).
// SPLITK: z = K-chunk index (kbeg=z*chunk), outf += z*oBatch (f32 partials).
// !SPLITK: z batches a0/Bm/rs/outb (PU).
// EPI: 4 -> outb[ix]=bf16(acc*rs[row]) ; 5 -> outf[ix]=acc (f32 partial).
// C/D frag layout: row=(lane>>4)*4+reg, col=lane&15 (HW-verified).
// ---------------------------------------------------------------------------
template <int NSRC, int EPI, bool SPLITK, bool BTRANS>
__global__ __launch_bounds__(256) void mfma3(
    const unsigned short* __restrict__ a0, const unsigned short* __restrict__ a1,
    const unsigned short* __restrict__ a2, int arstride, long aBatch,
    const unsigned short* __restrict__ Bm, int bstride, long wBatch, int wmask,
    int N, int Kd, int chunk,
    const float* __restrict__ rs, long rsBatch,
    float* __restrict__ outf, unsigned short* __restrict__ outb, long oBatch) {
    constexpr int LDA = 72;
    __shared__ unsigned short Als[2][64 * LDA];
    __shared__ unsigned short Bls[2][64 * LDA];

    const int z = blockIdx.z;
    int kbeg;
    if (SPLITK) {
        kbeg = z * chunk;
        outf += (size_t)z * oBatch;
    } else {
        kbeg = 0;
        chunk = Kd;
        a0 += (size_t)z * aBatch;
        Bm += (size_t)(z & wmask) * wBatch;
        if (rs) rs += (size_t)z * rsBatch;
        if (outb) outb += (size_t)z * oBatch;
    }
    const int kend = kbeg + chunk;

    const int tid = threadIdx.x;
    const int wave = tid >> 6, lane = tid & 63;
    const int wr = wave >> 1, wc = wave & 1;
    const int l15 = lane & 15, lg = lane >> 4;
    const int row0 = blockIdx.y * 64, col0 = blockIdx.x * 64;
    const int srow = tid >> 2, skc = (tid & 3) * 16;

    f32x4 acc[2][2] = {};
    ushort8 ra0, ra1, rb0, rb1;

    // ---- load k-slab kb into regs ----
#define LOAD_SLAB(kb)                                                                  \
    {                                                                                  \
        int kglob = (kb) + skc;                                                        \
        const unsigned short* asrc = a0;                                               \
        int kl = kglob;                                                                \
        if (NSRC > 1) {                                                                \
            int s = kglob >> 10;                                                       \
            kl = kglob & 1023;                                                         \
            asrc = (s == 0) ? a0 : ((s == 1 || NSRC == 2) ? a1 : a2);                  \
        }                                                                              \
        const unsigned short* p = asrc + (size_t)(row0 + srow) * arstride + kl;        \
        ra0 = *(const ushort8*)p;                                                      \
        ra1 = *(const ushort8*)(p + 8);                                                \
        if (BTRANS) {                                                                  \
            const unsigned short* q = Bm + (size_t)((kb) + srow) * bstride + col0 + skc; \
            rb0 = *(const ushort8*)q;                                                  \
            rb1 = *(const ushort8*)(q + 8);                                            \
        } else {                                                                       \
            int col = col0 + srow;                                                     \
            if (col < N) {                                                             \
                const unsigned short* q = Bm + (size_t)col * bstride + kglob;          \
                rb0 = *(const ushort8*)q;                                              \
                rb1 = *(const ushort8*)(q + 8);                                        \
            } else {                                                                   \
                ushort8 z8 = {};                                                       \
                rb0 = z8;                                                              \
                rb1 = z8;                                                              \
            }                                                                          \
        }                                                                              \
    }

#define WRITE_SLAB(b)                                                                  \
    {                                                                                  \
        *(ushort8*)&Als[b][srow * LDA + skc] = ra0;                                    \
        *(ushort8*)&Als[b][srow * LDA + skc + 8] = ra1;                                \
        if (BTRANS) {                                                                  \
            _Pragma("unroll") for (int j = 0; j < 8; ++j)                              \
                Bls[b][(skc + j) * LDA + srow] = rb0[j];                               \
            _Pragma("unroll") for (int j = 0; j < 8; ++j)                              \
                Bls[b][(skc + 8 + j) * LDA + srow] = rb1[j];                           \
        } else {                                                                       \
            *(ushort8*)&Bls[b][srow * LDA + skc] = rb0;                                \
            *(ushort8*)&Bls[b][srow * LDA + skc + 8] = rb1;                            \
        }                                                                              \
    }

    LOAD_SLAB(kbeg);
    WRITE_SLAB(0);
    __syncthreads();

    int cur = 0;
    for (int k0 = kbeg; k0 < kend; k0 += 64) {
        const bool more = (k0 + 64 < kend);
        if (more) LOAD_SLAB(k0 + 64);   // issue early: latency hides under MFMA
#pragma unroll
        for (int h = 0; h < 2; ++h) {
            short8 af0 = *(const short8*)&Als[cur][(wr * 32 + l15) * LDA + h * 32 + lg * 8];
            short8 af1 = *(const short8*)&Als[cur][(wr * 32 + 16 + l15) * LDA + h * 32 + lg * 8];
            short8 bf0 = *(const short8*)&Bls[cur][(wc * 32 + l15) * LDA + h * 32 + lg * 8];
            short8 bf1 = *(const short8*)&Bls[cur][(wc * 32 + 16 + l15) * LDA + h * 32 + lg * 8];
            acc[0][0] = __builtin_amdgcn_mfma_f32_16x16x32_bf16(af0, bf0, acc[0][0], 0, 0, 0);
            acc[0][1] = __builtin_amdgcn_mfma_f32_16x16x32_bf16(af0, bf1, acc[0][1], 0, 0, 0);
            acc[1][0] = __builtin_amdgcn_mfma_f32_16x16x32_bf16(af1, bf0, acc[1][0], 0, 0, 0);
            acc[1][1] = __builtin_amdgcn_mfma_f32_16x16x32_bf16(af1, bf1, acc[1][1], 0, 0, 0);
        }
        if (more) {
            int nb = cur ^ 1;
            WRITE_SLAB(nb);      // other buffer: no conflict with cur readers
            __syncthreads();     // one barrier per K-64
            cur = nb;
        }
    }
#undef LOAD_SLAB
#undef WRITE_SLAB

#pragma unroll
    for (int m = 0; m < 2; ++m)
#pragma unroll
        for (int n = 0; n < 2; ++n)
#pragma unroll
            for (int r = 0; r < 4; ++r) {
                int row = row0 + wr * 32 + m * 16 + lg * 4 + r;
                int col = col0 + wc * 32 + n * 16 + l15;
                if (col >= N) continue;
                size_t ix = (size_t)row * N + col;
                if (EPI == 5) outf[ix] = acc[m][n][r];
                else if (EPI == 4) outb[ix] = f2b(acc[m][n][r] * rs[row]);
            }
}

// ---------------------------------------------------------------------------
// reduce-4-partials + activation.
// ACT 1: outb=bf16(tanh v); 2: outb=bf16(v); 3: g=sig(v+bias[col]),
//        r=g*b2f(e1)+(1-g)*b2f(e2), outb=bf16(r), outf?=r (in-place e1==outb ok);
// ACT 6: outb=bf16(v+bias[col])
// ---------------------------------------------------------------------------
template <int ACT>
__global__ __launch_bounds__(256) void ep2_k(const float* __restrict__ PF, long pstride,
                                             const float* __restrict__ bias,
                                             const unsigned short* e1,
                                             const unsigned short* e2,
                                             float* outf, unsigned short* outb,
                                             int total, int N) {
    int idx = blockIdx.x * 256 + threadIdx.x;
    if (idx >= total) return;
    float v = PF[idx] + PF[pstride + idx] + PF[2 * pstride + idx] + PF[3 * pstride + idx];
    int col = idx - (idx / N) * N;
    if (ACT == 1) {
        outb[idx] = f2b(tanhf(v));
    } else if (ACT == 2) {
        outb[idx] = f2b(v);
    } else if (ACT == 3) {
        float g = sigmoidf_(v + bias[col]);
        float r = g * b2f(e1[idx]) + (1.0f - g) * b2f(e2[idx]);
        if (outf) outf[idx] = r;
        outb[idx] = f2b(r);
    } else if (ACT == 6) {
        outb[idx] = f2b(v + bias[col]);
    }
}

// ---------------------------------------------------------------------------
// Scorer (bf16 l|r inputs, stride 300): scores (+)= relu(l_i + r_j + d) @ Wo + bo
// ---------------------------------------------------------------------------
template <bool ADD>
__global__ __launch_bounds__(256) void scorer_k(const unsigned short* __restrict__ Lm,
                                                const unsigned short* __restrict__ Rm,
                                                int lst,
                                                const float* __restrict__ dtab,
                                                const int* __restrict__ sb,
                                                const int* __restrict__ se,
                                                const float* __restrict__ Wo,
                                                const float* __restrict__ bo,
                                                float* __restrict__ scores) {
    const int b = blockIdx.z;
    const int i0 = blockIdx.y * 16;
    const int j0 = blockIdx.x * 16;
    __shared__ float Ll[16 * 151];
    __shared__ float Rl[16 * 151];
    __shared__ float Dl[NBc * 151];
    __shared__ float Wol[Hc * Lc];
    __shared__ float bol[Lc];
    const int tid = threadIdx.x;
    for (int idx = tid; idx < 16 * Hc; idx += 256) {
        int r = idx / Hc, c = idx - r * Hc;
        Ll[r * 151 + c] = b2f(Lm[(size_t)(b * Kc + i0 + r) * lst + c]);
        Rl[r * 151 + c] = b2f(Rm[(size_t)(b * Kc + j0 + r) * lst + c]);
    }
    for (int idx = tid; idx < NBc * Hc; idx += 256) {
        int r = idx / Hc, c = idx - r * Hc;
        Dl[r * 151 + c] = dtab[r * Hc + c];
    }
    for (int idx = tid; idx < Hc * Lc; idx += 256) Wol[idx] = Wo[idx];
    if (tid < Lc) bol[tid] = bo[tid];
    __syncthreads();

    const int ty = tid >> 4, tx = tid & 15;
    const int i = i0 + ty, j = j0 + tx;
    int d = sb[b * Kc + j] - se[b * Kc + i];
    int da = d < 0 ? -d : d;
    int bucket = (da <= 4) ? da : min(31 - __clz(da) + 3, NBc - 1);
    const float* lp = &Ll[ty * 151];
    const float* rp = &Rl[tx * 151];
    const float* dp = &Dl[bucket * 151];
    float acc[Lc] = {};
    for (int h = 0; h < Hc; ++h) {
        float v = lp[h] + rp[h] + dp[h];
        v = fmaxf(v, 0.0f);
#pragma unroll
        for (int l = 0; l < Lc; ++l) acc[l] = fmaf(v, Wol[h * Lc + l], acc[l]);
    }
    size_t base = (((size_t)(b * Kc + i)) * Kc + j) * Lc;
#pragma unroll
    for (int l = 0; l < Lc; ++l) {
        float v = acc[l] + bol[l];
        if (ADD) v += scores[base + l];
        scores[base + l] = v;
    }
}

// probs -> PRbf (bf16 only)
__global__ __launch_bounds__(256) void probs_k(const float* __restrict__ scores,
                                               const float* __restrict__ mask,
                                               unsigned short* __restrict__ PRbf) {
    int idx = blockIdx.x * 256 + threadIdx.x;
    if (idx >= Bc * Kc * Kc) return;
    const float* s = scores + (size_t)idx * Lc;
    float m = s[0];
#pragma unroll
    for (int l = 1; l < Lc; ++l) m = fmaxf(m, s[l]);
    PRbf[idx] = f2b(sigmoidf_(m) * mask[idx]);
}

// rowsum over bf16 probs
__global__ __launch_bounds__(256) void rowsum_k(const unsigned short* __restrict__ probs,
                                                float* __restrict__ s1inv) {
    int row = (blockIdx.x * 256 + threadIdx.x) >> 6;
    int lane = threadIdx.x & 63;
    if (row >= Mrows) return;
    const unsigned short* p = probs + (size_t)row * Kc;
    float s = 0.0f;
    for (int j = lane; j < Kc; j += 64) s += b2f(p[j]);
#pragma unroll
    for (int off = 32; off > 0; off >>= 1) s += __shfl_down(s, off);
    if (lane == 0) s1inv[row] = 1.0f / (s + 1e-7f);
}

// colsum over bf16 probs
__global__ __launch_bounds__(256) void colsum_k(const unsigned short* __restrict__ probs,
                                                float* __restrict__ s2inv) {
    int idx = blockIdx.x * 256 + threadIdx.x;
    if (idx >= Mrows) return;
    int b = idx / Kc, j = idx - b * Kc;
    const unsigned short* p = probs + (size_t)b * Kc * Kc + j;
    float s = 0.0f;
    for (int i = 0; i < Kc; ++i) s += b2f(p[(size_t)i * Kc]);
    s2inv[idx] = 1.0f / (s + 1e-7f);
}

__global__ __launch_bounds__(256) void copy4_k(const float4* __restrict__ s,
                                               float4* __restrict__ d, int n4) {
    int i = blockIdx.x * 256 + threadIdx.x;
    if (i < n4) d[i] = s[i];
}

// scatter: numpy sequential-set semantics
__global__ __launch_bounds__(256) void scatter_k(const float* __restrict__ Uf,
                                                 const int* __restrict__ pidx,
                                                 const int* __restrict__ slen,
                                                 float* __restrict__ out_all) {
    int bk = blockIdx.x;
    int b = bk / Kc, k = bk - b * Kc;
    if (k >= slen[b]) return;
    int idx = pidx[bk];
    if (k + 1 < Kc && pidx[bk + 1] == idx) return;
    const float4* s = (const float4*)(Uf + (size_t)bk * Dc);
    float4* d = (float4*)(out_all + ((size_t)b * Nc + idx) * Dc);
    for (int c = threadIdx.x; c < Dc / 4; c += 256) d[c] = s[c];
}

// ---------------------------------------------------------------------------
extern "C" void kernel_launch(void* const* d_in, const int* in_sizes, int n_in,
                              void* d_out, int out_size, void* d_ws, size_t ws_size,
                              hipStream_t stream) {
    const float* span_vecs = (const float*)d_in[0];
    const float* all_span_vecs = (const float*)d_in[1];
    const int* span_begin = (const int*)d_in[2];
    const int* span_end = (const int*)d_in[3];
    const float* square_mask = (const float*)d_in[4];
    const int* prune_indices = (const int*)d_in[5];
    const int* span_lengths = (const int*)d_in[6];
    const float* Wl = (const float*)d_in[8];
    const float* bl = (const float*)d_in[9];
    const float* Wr = (const float*)d_in[10];
    const float* br = (const float*)d_in[11];
    const float* dist_emb = (const float*)d_in[12];
    const float* Wd = (const float*)d_in[13];
    const float* bd = (const float*)d_in[14];
    const float* Wo = (const float*)d_in[15];
    const float* bo = (const float*)d_in[16];
    const float* Wff1 = (const float*)d_in[17];
    const float* Wff2 = (const float*)d_in[18];
    const float* Wg = (const float*)d_in[19];
    const float* bg = (const float*)d_in[20];

    float* out_all = (float*)d_out;                    // B*N*D = 8,388,608 floats
    float* out_u = out_all + (size_t)Bc * Nc * Dc;     // B*K*D
    float* out_sc = out_u + (size_t)Mrows * Dc;        // B*K*K*L

    // Scratch in out_all (dead until final copy). Offsets (floats), 64-aligned.
    float* w = out_all;
    float* DT = w;                                          // 1,600
    float* S1 = w + 1600;                                   // [4][384] f32
    unsigned short* LRMb = (unsigned short*)(w + 3136);     // [768][300] bf16
    unsigned short* Ubf = (unsigned short*)(w + 118336);    // [768][1024] bf16
    unsigned short* Cbf = (unsigned short*)(w + 511552);    // [4][384][1024] bf16
    unsigned short* T1bf = (unsigned short*)(w + 1297984);  // [768][1024]? no: 393,216 sh
    unsigned short* PRbf = (unsigned short*)(w + 1494592);  // [4][384][384] bf16
    float* PF = w + 1789504;                                // [4][768][1024] f32
    unsigned short* Wff1T = (unsigned short*)(w + 4935232); // [1024][3072]
    unsigned short* Wff2T = (unsigned short*)(w + 6508096); // [1024][1024]
    unsigned short* WgT = (unsigned short*)(w + 7032384);   // [1024][2048]
    unsigned short* WlrT = (unsigned short*)(w + 8080960);  // [300][1024]
    float* blr = w + 8234560;                               // 320 -> end 8,234,880
    const long KK = (long)Kc * Kc;   // 147,456
    const long KD = (long)Kc * Dc;   // 393,216
    unsigned short* C1bf = Cbf;                  // z0,z1 = ctxt1 b0,b1
    unsigned short* C2bf = Cbf + 2 * KD;         // z2,z3 = ctxt2 b0,b1
    unsigned short* PT = PRbf + 2 * KK;
    unsigned short* CTbf = C1bf;                 // alias: C1 dead after FF1
    const long PFS = (long)Mrows * Dc;           // 786,432 partial stride

    dim3 blk(256);
    dim3 g_sc(Kc / 16, Kc / 16, Bc);
    dim3 g_ff(16, 12, 4);   // 64x64 tiles, N=1024, M=768, S=4
    dim3 g_lr(5, 12, 4);    // N=300 (guarded), S=4
    dim3 g_pu(16, 6, 4);    // per-z M=384, z = {P b0, P b1, PT b0, PT b1}
    dim3 g_trp(12, 12, 2);

    // one-time conversions
    cvt_k<<<2048, blk, 0, stream>>>(span_vecs, Ubf, Mrows * Dc);
    trw_k<<<dim3(32, 96), blk, 0, stream>>>(Wff1, Wff1T, 3 * Dc, Dc);
    trw_k<<<dim3(32, 32), blk, 0, stream>>>(Wff2, Wff2T, Dc, Dc);
    trw_k<<<dim3(32, 64), blk, 0, stream>>>(Wg, WgT, 2 * Dc, Dc);
    trwlr_k<<<(2 * Hc * Dc + 255) / 256, blk, 0, stream>>>(Wl, Wr, bl, br, WlrT, blr);
    dtab_k<<<(NBc * Hc + 255) / 256, blk, 0, stream>>>(dist_emb, Wd, bd, DT);

    const int TFF = Mrows * Dc;       // 786,432
    const int TLR = Mrows * 2 * Hc;   // 230,400

    // initial l|r projection + scorer
    mfma3<1, 5, true, false><<<g_lr, blk, 0, stream>>>(
        Ubf, nullptr, nullptr, Dc, 0, WlrT, Dc, 0, 0, 2 * Hc, Dc, 256,
        nullptr, 0, PF, nullptr, TLR);
    ep2_k<6><<<(TLR + 255) / 256, blk, 0, stream>>>(PF, TLR, blr, nullptr, nullptr,
                                                    nullptr, LRMb, TLR, 2 * Hc);
    scorer_k<false><<<g_sc, blk, 0, stream>>>(LRMb, LRMb + Hc, 2 * Hc, DT,
                                              span_begin, span_end, Wo, bo, out_sc);

    for (int it = 0; it < 2; ++it) {
        probs_k<<<(Bc * Kc * Kc + 255) / 256, blk, 0, stream>>>(out_sc, square_mask, PRbf);
        rowsum_k<<<Mrows / 4, blk, 0, stream>>>(PRbf, S1);
        colsum_k<<<(Mrows + 255) / 256, blk, 0, stream>>>(PRbf, S1 + Mrows);
        trb_k<<<g_trp, blk, 0, stream>>>(PRbf, PT, Kc, Kc, KK, KK);
        // fused PU (direct bf16 out, rs scale): A=PRbf+z*KK, B=Ubf+(z&1)*KD (BTRANS)
        mfma3<1, 4, false, true><<<g_pu, blk, 0, stream>>>(
            PRbf, nullptr, nullptr, Kc, KK, Ubf, Dc, KD, 1, Dc, Kc, Kc,
            S1, Kc, nullptr, Cbf, KD);
        // FF1: T1 = tanh([U|C1|C2] @ Wff1)
        mfma3<3, 5, true, false><<<g_ff, blk, 0, stream>>>(
            Ubf, C1bf, C2bf, Dc, 0, Wff1T, 3 * Dc, 0, 0, Dc, 3 * Dc, 768,
            nullptr, 0, PF, nullptr, PFS);
        ep2_k<1><<<(TFF + 255) / 256, blk, 0, stream>>>(PF, PFS, nullptr, nullptr, nullptr,
                                                        nullptr, T1bf, TFF, Dc);
        // FF2: CT = T1 @ Wff2 (bf16, overwrites C1 region)
        mfma3<1, 5, true, false><<<g_ff, blk, 0, stream>>>(
            T1bf, nullptr, nullptr, Dc, 0, Wff2T, Dc, 0, 0, Dc, Dc, 256,
            nullptr, 0, PF, nullptr, PFS);
        ep2_k<2><<<(TFF + 255) / 256, blk, 0, stream>>>(PF, PFS, nullptr, nullptr, nullptr,
                                                        nullptr, CTbf, TFF, Dc);
        // gate: g = sig([U|CT]@Wg + bg); u' = g*u + (1-g)*CT  (in-place Ubf; final f32)
        mfma3<2, 5, true, false><<<g_ff, blk, 0, stream>>>(
            Ubf, CTbf, nullptr, Dc, 0, WgT, 2 * Dc, 0, 0, Dc, 2 * Dc, 512,
            nullptr, 0, PF, nullptr, PFS);
        ep2_k<3><<<(TFF + 255) / 256, blk, 0, stream>>>(PF, PFS, bg, Ubf, CTbf,
                                                        (it == 1) ? out_u : nullptr,
                                                        Ubf, TFF, Dc);
        // next l|r + scorer (residual add)
        mfma3<1, 5, true, false><<<g_lr, blk, 0, stream>>>(
            Ubf, nullptr, nullptr, Dc, 0, WlrT, Dc, 0, 0, 2 * Hc, Dc, 256,
            nullptr, 0, PF, nullptr, TLR);
        ep2_k<6><<<(TLR + 255) / 256, blk, 0, stream>>>(PF, TLR, blr, nullptr, nullptr,
                                                        nullptr, LRMb, TLR, 2 * Hc);
        scorer_k<true><<<g_sc, blk, 0, stream>>>(LRMb, LRMb + Hc, 2 * Hc, DT,
                                                 span_begin, span_end, Wo, bo, out_sc);
    }

    // out_u written by final ep2<3>. Fill out_all, then scatter.
    copy4_k<<<((Bc * Nc * Dc / 4) + 255) / 256, blk, 0, stream>>>(
        (const float4*)all_span_vecs, (float4*)out_all, Bc * Nc * Dc / 4);
    scatter_k<<<Mrows, blk, 0, stream>>>(out_u, prune_indices, span_lengths, out_all);
}

// Round 11
// 424.018 us; speedup vs baseline: 1.6002x; 1.0755x over previous
//
#include <hip/hip_runtime.h>
#include <math.h>

// Problem constants (match reference)
constexpr int Bc = 2, Kc = 384, Nc = 4096, Dc = 1024;
constexpr int Hc = 150, Lc = 12, DDc = 20, NBc = 10;
constexpr int Mrows = Bc * Kc; // 768

typedef __attribute__((ext_vector_type(8))) unsigned short ushort8;
typedef __attribute__((ext_vector_type(8))) short short8;
typedef __attribute__((ext_vector_type(4))) float f32x4;

__device__ __forceinline__ float sigmoidf_(float x) { return 1.0f / (1.0f + expf(-x)); }

__device__ __forceinline__ unsigned short f2b(float f) {
    unsigned u = __float_as_uint(f);
    unsigned r = (u + 0x7fffu + ((u >> 16) & 1u)) >> 16;
    return (unsigned short)r;
}
__device__ __forceinline__ float b2f(unsigned short u) {
    return __uint_as_float((unsigned)u << 16);
}

__global__ __launch_bounds__(256) void cvt_k(const float* __restrict__ s,
                                             unsigned short* __restrict__ d, int n) {
    for (int i = blockIdx.x * 256 + threadIdx.x; i < n; i += gridDim.x * 256)
        d[i] = f2b(s[i]);
}

// dist table (f32)
__global__ __launch_bounds__(256) void dtab_k(const float* __restrict__ de,
                                              const float* __restrict__ Wd,
                                              const float* __restrict__ bd,
                                              float* __restrict__ dtab) {
    int idx = blockIdx.x * 256 + threadIdx.x;
    if (idx >= NBc * Hc) return;
    int n = idx / Hc, h = idx - n * Hc;
    float s = bd[h];
#pragma unroll
    for (int k = 0; k < DDc; ++k) s = fmaf(de[n * DDc + k], Wd[k * Hc + h], s);
    dtab[n * Hc + h] = s;
}

// f32 W[K][N] -> bf16 WT[N][K]
__global__ __launch_bounds__(256) void trw_k(const float* __restrict__ Wsrc,
                                             unsigned short* __restrict__ WT,
                                             int K, int N) {
    __shared__ unsigned short t[32][33];
    const int k0 = blockIdx.y * 32, n0 = blockIdx.x * 32;
    const int tx = threadIdx.x & 31, ty = threadIdx.x >> 5;
#pragma unroll
    for (int i = 0; i < 4; ++i)
        t[ty + i * 8][tx] = f2b(Wsrc[(size_t)(k0 + ty + i * 8) * N + n0 + tx]);
    __syncthreads();
#pragma unroll
    for (int i = 0; i < 4; ++i)
        WT[(size_t)(n0 + ty + i * 8) * K + k0 + tx] = t[tx][ty + i * 8];
}

// WlrT[r][k] = bf16((r<150?Wl:Wr)[k][r%150]); blr = [bl|br]
__global__ __launch_bounds__(256) void trwlr_k(const float* __restrict__ Wl,
                                               const float* __restrict__ Wr,
                                               const float* __restrict__ bl,
                                               const float* __restrict__ br,
                                               unsigned short* __restrict__ WlrT,
                                               float* __restrict__ blr) {
    int idx = blockIdx.x * 256 + threadIdx.x;
    if (idx < Hc) { blr[idx] = bl[idx]; blr[Hc + idx] = br[idx]; }
    if (idx >= 2 * Hc * Dc) return;
    int r = idx >> 10, k = idx & 1023;
    float v = (r < Hc) ? Wl[(size_t)k * Hc + r] : Wr[(size_t)k * Hc + (r - Hc)];
    WlrT[idx] = f2b(v);
}

// bf16 tile transpose: dst[z][C][R] = src[z][R][C]^T
__global__ __launch_bounds__(256) void trb_k(const unsigned short* __restrict__ src,
                                             unsigned short* __restrict__ dst,
                                             int R, int C, long sBatch, long dBatch) {
    __shared__ unsigned short t[32][33];
    const int z = blockIdx.z;
    src += (size_t)z * sBatch;
    dst += (size_t)z * dBatch;
    const int r0 = blockIdx.y * 32, c0 = blockIdx.x * 32;
    const int tx = threadIdx.x & 31, ty = threadIdx.x >> 5;
#pragma unroll
    for (int i = 0; i < 4; ++i)
        t[ty + i * 8][tx] = src[(size_t)(r0 + ty + i * 8) * C + c0 + tx];
    __syncthreads();
#pragma unroll
    for (int i = 0; i < 4; ++i)
        dst[(size_t)(c0 + ty + i * 8) * R + r0 + tx] = t[tx][ty + i * 8];
}

// ---------------------------------------------------------------------------
// mfma3: 64x64 tile, 4 waves x (2x2 16x16 frags), K-step 64, double-buffered
// LDS, prefetch-to-regs before compute, ONE barrier per K-step. (round-10)
// ---------------------------------------------------------------------------
template <int NSRC, int EPI, bool SPLITK, bool BTRANS>
__global__ __launch_bounds__(256) void mfma3(
    const unsigned short* __restrict__ a0, const unsigned short* __restrict__ a1,
    const unsigned short* __restrict__ a2, int arstride, long aBatch,
    const unsigned short* __restrict__ Bm, int bstride, long wBatch, int wmask,
    int N, int Kd, int chunk,
    const float* __restrict__ rs, long rsBatch,
    float* __restrict__ outf, unsigned short* __restrict__ outb, long oBatch) {
    constexpr int LDA = 72;
    __shared__ unsigned short Als[2][64 * LDA];
    __shared__ unsigned short Bls[2][64 * LDA];

    const int z = blockIdx.z;
    int kbeg;
    if (SPLITK) {
        kbeg = z * chunk;
        outf += (size_t)z * oBatch;
    } else {
        kbeg = 0;
        chunk = Kd;
        a0 += (size_t)z * aBatch;
        Bm += (size_t)(z & wmask) * wBatch;
        if (rs) rs += (size_t)z * rsBatch;
        if (outb) outb += (size_t)z * oBatch;
    }
    const int kend = kbeg + chunk;

    const int tid = threadIdx.x;
    const int wave = tid >> 6, lane = tid & 63;
    const int wr = wave >> 1, wc = wave & 1;
    const int l15 = lane & 15, lg = lane >> 4;
    const int row0 = blockIdx.y * 64, col0 = blockIdx.x * 64;
    const int srow = tid >> 2, skc = (tid & 3) * 16;

    f32x4 acc[2][2] = {};
    ushort8 ra0, ra1, rb0, rb1;

#define LOAD_SLAB(kb)                                                                  \
    {                                                                                  \
        int kglob = (kb) + skc;                                                        \
        const unsigned short* asrc = a0;                                               \
        int kl = kglob;                                                                \
        if (NSRC > 1) {                                                                \
            int s = kglob >> 10;                                                       \
            kl = kglob & 1023;                                                         \
            asrc = (s == 0) ? a0 : ((s == 1 || NSRC == 2) ? a1 : a2);                  \
        }                                                                              \
        const unsigned short* p = asrc + (size_t)(row0 + srow) * arstride + kl;        \
        ra0 = *(const ushort8*)p;                                                      \
        ra1 = *(const ushort8*)(p + 8);                                                \
        if (BTRANS) {                                                                  \
            const unsigned short* q = Bm + (size_t)((kb) + srow) * bstride + col0 + skc; \
            rb0 = *(const ushort8*)q;                                                  \
            rb1 = *(const ushort8*)(q + 8);                                            \
        } else {                                                                       \
            int col = col0 + srow;                                                     \
            if (col < N) {                                                             \
                const unsigned short* q = Bm + (size_t)col * bstride + kglob;          \
                rb0 = *(const ushort8*)q;                                              \
                rb1 = *(const ushort8*)(q + 8);                                        \
            } else {                                                                   \
                ushort8 z8 = {};                                                       \
                rb0 = z8;                                                              \
                rb1 = z8;                                                              \
            }                                                                          \
        }                                                                              \
    }

#define WRITE_SLAB(b)                                                                  \
    {                                                                                  \
        *(ushort8*)&Als[b][srow * LDA + skc] = ra0;                                    \
        *(ushort8*)&Als[b][srow * LDA + skc + 8] = ra1;                                \
        if (BTRANS) {                                                                  \
            _Pragma("unroll") for (int j = 0; j < 8; ++j)                              \
                Bls[b][(skc + j) * LDA + srow] = rb0[j];                               \
            _Pragma("unroll") for (int j = 0; j < 8; ++j)                              \
                Bls[b][(skc + 8 + j) * LDA + srow] = rb1[j];                           \
        } else {                                                                       \
            *(ushort8*)&Bls[b][srow * LDA + skc] = rb0;                                \
            *(ushort8*)&Bls[b][srow * LDA + skc + 8] = rb1;                            \
        }                                                                              \
    }

    LOAD_SLAB(kbeg);
    WRITE_SLAB(0);
    __syncthreads();

    int cur = 0;
    for (int k0 = kbeg; k0 < kend; k0 += 64) {
        const bool more = (k0 + 64 < kend);
        if (more) LOAD_SLAB(k0 + 64);
#pragma unroll
        for (int h = 0; h < 2; ++h) {
            short8 af0 = *(const short8*)&Als[cur][(wr * 32 + l15) * LDA + h * 32 + lg * 8];
            short8 af1 = *(const short8*)&Als[cur][(wr * 32 + 16 + l15) * LDA + h * 32 + lg * 8];
            short8 bf0 = *(const short8*)&Bls[cur][(wc * 32 + l15) * LDA + h * 32 + lg * 8];
            short8 bf1 = *(const short8*)&Bls[cur][(wc * 32 + 16 + l15) * LDA + h * 32 + lg * 8];
            acc[0][0] = __builtin_amdgcn_mfma_f32_16x16x32_bf16(af0, bf0, acc[0][0], 0, 0, 0);
            acc[0][1] = __builtin_amdgcn_mfma_f32_16x16x32_bf16(af0, bf1, acc[0][1], 0, 0, 0);
            acc[1][0] = __builtin_amdgcn_mfma_f32_16x16x32_bf16(af1, bf0, acc[1][0], 0, 0, 0);
            acc[1][1] = __builtin_amdgcn_mfma_f32_16x16x32_bf16(af1, bf1, acc[1][1], 0, 0, 0);
        }
        if (more) {
            int nb = cur ^ 1;
            WRITE_SLAB(nb);
            __syncthreads();
            cur = nb;
        }
    }
#undef LOAD_SLAB
#undef WRITE_SLAB

#pragma unroll
    for (int m = 0; m < 2; ++m)
#pragma unroll
        for (int n = 0; n < 2; ++n)
#pragma unroll
            for (int r = 0; r < 4; ++r) {
                int row = row0 + wr * 32 + m * 16 + lg * 4 + r;
                int col = col0 + wc * 32 + n * 16 + l15;
                if (col >= N) continue;
                size_t ix = (size_t)row * N + col;
                if (EPI == 5) outf[ix] = acc[m][n][r];
                else if (EPI == 4) outb[ix] = f2b(acc[m][n][r] * rs[row]);
            }
}

// ---------------------------------------------------------------------------
// reduce-4-partials + activation (round-10)
// ---------------------------------------------------------------------------
template <int ACT>
__global__ __launch_bounds__(256) void ep2_k(const float* __restrict__ PF, long pstride,
                                             const float* __restrict__ bias,
                                             const unsigned short* e1,
                                             const unsigned short* e2,
                                             float* outf, unsigned short* outb,
                                             int total, int N) {
    int idx = blockIdx.x * 256 + threadIdx.x;
    if (idx >= total) return;
    float v = PF[idx] + PF[pstride + idx] + PF[2 * pstride + idx] + PF[3 * pstride + idx];
    int col = idx - (idx / N) * N;
    if (ACT == 1) {
        outb[idx] = f2b(tanhf(v));
    } else if (ACT == 2) {
        outb[idx] = f2b(v);
    } else if (ACT == 3) {
        float g = sigmoidf_(v + bias[col]);
        float r = g * b2f(e1[idx]) + (1.0f - g) * b2f(e2[idx]);
        if (outf) outf[idx] = r;
        outb[idx] = f2b(r);
    } else if (ACT == 6) {
        outb[idx] = f2b(v + bias[col]);
    }
}

// ---------------------------------------------------------------------------
// scorer2: MFMA scorer. Per block: 16x16 (i,j) tile. Per j-column jg, a
// 16(pairs) x 160(K,pad) x 16 mini-GEMM: A = relu(l_i + r_j + d_bucket) built
// in-register (bf16-trunc pack), B = Wo frags preloaded. One wave per 4
// columns, 5 MFMA each. C/D: row=(lane>>4)*4+reg, col=lane&15. A and B use
// the same (lane,j)->k mapping so any k-permutation cancels.
// ---------------------------------------------------------------------------
template <bool ADD>
__global__ __launch_bounds__(256) void scorer2_k(
    const unsigned short* __restrict__ Lm, const unsigned short* __restrict__ Rm,
    int lst, const float* __restrict__ dtab,
    const int* __restrict__ sb, const int* __restrict__ se,
    const float* __restrict__ Wo, const float* __restrict__ bo,
    float* __restrict__ scores) {
    const int b = blockIdx.z;
    const int i0 = blockIdx.y * 16, j0 = blockIdx.x * 16;
    __shared__ unsigned short Lb[16 * 168];
    __shared__ unsigned short Rb[16 * 168];
    __shared__ float Df[10 * 164];
    __shared__ int sbs[16];
    const int tid = threadIdx.x;
    const int wave = tid >> 6, lane = tid & 63;
    const int l15 = lane & 15, lg = lane >> 4;

    for (int idx = tid; idx < 16 * 160; idx += 256) {
        int r = idx / 160, c = idx - r * 160;
        Lb[r * 168 + c] = (c < Hc) ? Lm[(size_t)(b * Kc + i0 + r) * lst + c] : (unsigned short)0;
        Rb[r * 168 + c] = (c < Hc) ? Rm[(size_t)(b * Kc + j0 + r) * lst + c] : (unsigned short)0;
    }
    for (int idx = tid; idx < 10 * 160; idx += 256) {
        int r = idx / 160, c = idx - r * 160;
        Df[r * 164 + c] = (c < Hc) ? dtab[r * Hc + c] : 0.0f;
    }
    if (tid < 16) sbs[tid] = sb[b * Kc + j0 + tid];

    // Wo B-frags (5 x short8), k = kc*32 + lg*8 + j, col = l15
    short8 bfr[5];
#pragma unroll
    for (int kc = 0; kc < 5; ++kc) {
#pragma unroll
        for (int j = 0; j < 8; ++j) {
            int k = kc * 32 + lg * 8 + j;
            float v = (k < Hc && l15 < Lc) ? Wo[k * Lc + l15] : 0.0f;
            bfr[kc][j] = f2b(v);
        }
    }
    const int se_i = se[b * Kc + i0 + l15];
    const float bo_l = (l15 < Lc) ? bo[l15] : 0.0f;
    __syncthreads();

#pragma unroll
    for (int t = 0; t < 4; ++t) {
        const int jg = wave * 4 + t;
        int d = sbs[jg] - se_i;
        int da = d < 0 ? -d : d;
        int bucket = (da <= 4) ? da : min(31 - __clz(da) + 3, NBc - 1);
        const float* dp = &Df[bucket * 164];
        f32x4 acc = {};
#pragma unroll
        for (int kc = 0; kc < 5; ++kc) {
            int h0 = kc * 32 + lg * 8;
            ushort8 La = *(const ushort8*)&Lb[l15 * 168 + h0];
            ushort8 Ra = *(const ushort8*)&Rb[jg * 168 + h0];
            f32x4 D0 = *(const f32x4*)&dp[h0];
            f32x4 D1 = *(const f32x4*)&dp[h0 + 4];
            const unsigned* lu = (const unsigned*)&La;
            const unsigned* ru = (const unsigned*)&Ra;
            union { unsigned u[4]; short8 s; } aw;
#pragma unroll
            for (int q = 0; q < 4; ++q) {
                float de0 = (q < 2) ? D0[2 * q] : D1[2 * q - 4];
                float de1 = (q < 2) ? D0[2 * q + 1] : D1[2 * q - 3];
                float lv0 = __uint_as_float(lu[q] << 16);
                float lv1 = __uint_as_float(lu[q] & 0xffff0000u);
                float rv0 = __uint_as_float(ru[q] << 16);
                float rv1 = __uint_as_float(ru[q] & 0xffff0000u);
                float s0 = fmaxf(lv0 + rv0 + de0, 0.0f);
                float s1 = fmaxf(lv1 + rv1 + de1, 0.0f);
                aw.u[q] = (__float_as_uint(s0) >> 16) | (__float_as_uint(s1) & 0xffff0000u);
            }
            acc = __builtin_amdgcn_mfma_f32_16x16x32_bf16(aw.s, bfr[kc], acc, 0, 0, 0);
        }
        if (l15 < Lc) {
#pragma unroll
            for (int r = 0; r < 4; ++r) {
                int irow = lg * 4 + r;
                size_t off = (((size_t)(b * Kc + i0 + irow)) * Kc + (j0 + jg)) * Lc + l15;
                float v = acc[r] + bo_l;
                if (ADD) v += scores[off];
                scores[off] = v;
            }
        }
    }
}

// probs -> PRbf (bf16 only)
__global__ __launch_bounds__(256) void probs_k(const float* __restrict__ scores,
                                               const float* __restrict__ mask,
                                               unsigned short* __restrict__ PRbf) {
    int idx = blockIdx.x * 256 + threadIdx.x;
    if (idx >= Bc * Kc * Kc) return;
    const float* s = scores + (size_t)idx * Lc;
    float m = s[0];
#pragma unroll
    for (int l = 1; l < Lc; ++l) m = fmaxf(m, s[l]);
    PRbf[idx] = f2b(sigmoidf_(m) * mask[idx]);
}

// rowsum over bf16 probs
__global__ __launch_bounds__(256) void rowsum_k(const unsigned short* __restrict__ probs,
                                                float* __restrict__ s1inv) {
    int row = (blockIdx.x * 256 + threadIdx.x) >> 6;
    int lane = threadIdx.x & 63;
    if (row >= Mrows) return;
    const unsigned short* p = probs + (size_t)row * Kc;
    float s = 0.0f;
    for (int j = lane; j < Kc; j += 64) s += b2f(p[j]);
#pragma unroll
    for (int off = 32; off > 0; off >>= 1) s += __shfl_down(s, off);
    if (lane == 0) s1inv[row] = 1.0f / (s + 1e-7f);
}

// colsum over bf16 probs
__global__ __launch_bounds__(256) void colsum_k(const unsigned short* __restrict__ probs,
                                                float* __restrict__ s2inv) {
    int idx = blockIdx.x * 256 + threadIdx.x;
    if (idx >= Mrows) return;
    int b = idx / Kc, j = idx - b * Kc;
    const unsigned short* p = probs + (size_t)b * Kc * Kc + j;
    float s = 0.0f;
    for (int i = 0; i < Kc; ++i) s += b2f(p[(size_t)i * Kc]);
    s2inv[idx] = 1.0f / (s + 1e-7f);
}

__global__ __launch_bounds__(256) void copy4_k(const float4* __restrict__ s,
                                               float4* __restrict__ d, int n4) {
    int i = blockIdx.x * 256 + threadIdx.x;
    if (i < n4) d[i] = s[i];
}

// scatter: numpy sequential-set semantics
__global__ __launch_bounds__(256) void scatter_k(const float* __restrict__ Uf,
                                                 const int* __restrict__ pidx,
                                                 const int* __restrict__ slen,
                                                 float* __restrict__ out_all) {
    int bk = blockIdx.x;
    int b = bk / Kc, k = bk - b * Kc;
    if (k >= slen[b]) return;
    int idx = pidx[bk];
    if (k + 1 < Kc && pidx[bk + 1] == idx) return;
    const float4* s = (const float4*)(Uf + (size_t)bk * Dc);
    float4* d = (float4*)(out_all + ((size_t)b * Nc + idx) * Dc);
    for (int c = threadIdx.x; c < Dc / 4; c += 256) d[c] = s[c];
}

// ---------------------------------------------------------------------------
extern "C" void kernel_launch(void* const* d_in, const int* in_sizes, int n_in,
                              void* d_out, int out_size, void* d_ws, size_t ws_size,
                              hipStream_t stream) {
    const float* span_vecs = (const float*)d_in[0];
    const float* all_span_vecs = (const float*)d_in[1];
    const int* span_begin = (const int*)d_in[2];
    const int* span_end = (const int*)d_in[3];
    const float* square_mask = (const float*)d_in[4];
    const int* prune_indices = (const int*)d_in[5];
    const int* span_lengths = (const int*)d_in[6];
    const float* Wl = (const float*)d_in[8];
    const float* bl = (const float*)d_in[9];
    const float* Wr = (const float*)d_in[10];
    const float* br = (const float*)d_in[11];
    const float* dist_emb = (const float*)d_in[12];
    const float* Wd = (const float*)d_in[13];
    const float* bd = (const float*)d_in[14];
    const float* Wo = (const float*)d_in[15];
    const float* bo = (const float*)d_in[16];
    const float* Wff1 = (const float*)d_in[17];
    const float* Wff2 = (const float*)d_in[18];
    const float* Wg = (const float*)d_in[19];
    const float* bg = (const float*)d_in[20];

    float* out_all = (float*)d_out;                    // B*N*D = 8,388,608 floats
    float* out_u = out_all + (size_t)Bc * Nc * Dc;     // B*K*D
    float* out_sc = out_u + (size_t)Mrows * Dc;        // B*K*K*L

    // Scratch in out_all (dead until final copy). Offsets (floats), 64-aligned.
    float* w = out_all;
    float* DT = w;                                          // 1,600
    float* S1 = w + 1600;                                   // [4][384] f32
    unsigned short* LRMb = (unsigned short*)(w + 3136);     // [768][300] bf16
    unsigned short* Ubf = (unsigned short*)(w + 118336);    // [768][1024] bf16
    unsigned short* Cbf = (unsigned short*)(w + 511552);    // [4][384][1024] bf16
    unsigned short* T1bf = (unsigned short*)(w + 1297984);  // 786,432 sh
    unsigned short* PRbf = (unsigned short*)(w + 1494592);  // [4][384][384] bf16
    float* PF = w + 1789504;                                // [4][768][1024] f32
    unsigned short* Wff1T = (unsigned short*)(w + 4935232); // [1024][3072]
    unsigned short* Wff2T = (unsigned short*)(w + 6508096); // [1024][1024]
    unsigned short* WgT = (unsigned short*)(w + 7032384);   // [1024][2048]
    unsigned short* WlrT = (unsigned short*)(w + 8080960);  // [300][1024]
    float* blr = w + 8234560;                               // 320 -> end 8,234,880
    const long KK = (long)Kc * Kc;   // 147,456
    const long KD = (long)Kc * Dc;   // 393,216
    unsigned short* C1bf = Cbf;
    unsigned short* C2bf = Cbf + 2 * KD;
    unsigned short* PT = PRbf + 2 * KK;
    unsigned short* CTbf = C1bf;                 // alias: C1 dead after FF1
    const long PFS = (long)Mrows * Dc;           // 786,432

    dim3 blk(256);
    dim3 g_sc(Kc / 16, Kc / 16, Bc);
    dim3 g_ff(16, 12, 4);
    dim3 g_lr(5, 12, 4);
    dim3 g_pu(16, 6, 4);
    dim3 g_trp(12, 12, 2);

    // one-time conversions
    cvt_k<<<2048, blk, 0, stream>>>(span_vecs, Ubf, Mrows * Dc);
    trw_k<<<dim3(32, 96), blk, 0, stream>>>(Wff1, Wff1T, 3 * Dc, Dc);
    trw_k<<<dim3(32, 32), blk, 0, stream>>>(Wff2, Wff2T, Dc, Dc);
    trw_k<<<dim3(32, 64), blk, 0, stream>>>(Wg, WgT, 2 * Dc, Dc);
    trwlr_k<<<(2 * Hc * Dc + 255) / 256, blk, 0, stream>>>(Wl, Wr, bl, br, WlrT, blr);
    dtab_k<<<(NBc * Hc + 255) / 256, blk, 0, stream>>>(dist_emb, Wd, bd, DT);

    const int TFF = Mrows * Dc;       // 786,432
    const int TLR = Mrows * 2 * Hc;   // 230,400

    // initial l|r projection + scorer
    mfma3<1, 5, true, false><<<g_lr, blk, 0, stream>>>(
        Ubf, nullptr, nullptr, Dc, 0, WlrT, Dc, 0, 0, 2 * Hc, Dc, 256,
        nullptr, 0, PF, nullptr, TLR);
    ep2_k<6><<<(TLR + 255) / 256, blk, 0, stream>>>(PF, TLR, blr, nullptr, nullptr,
                                                    nullptr, LRMb, TLR, 2 * Hc);
    scorer2_k<false><<<g_sc, blk, 0, stream>>>(LRMb, LRMb + Hc, 2 * Hc, DT,
                                               span_begin, span_end, Wo, bo, out_sc);

    for (int it = 0; it < 2; ++it) {
        probs_k<<<(Bc * Kc * Kc + 255) / 256, blk, 0, stream>>>(out_sc, square_mask, PRbf);
        rowsum_k<<<Mrows / 4, blk, 0, stream>>>(PRbf, S1);
        colsum_k<<<(Mrows + 255) / 256, blk, 0, stream>>>(PRbf, S1 + Mrows);
        trb_k<<<g_trp, blk, 0, stream>>>(PRbf, PT, Kc, Kc, KK, KK);
        // fused PU: A=PRbf+z*KK, B=Ubf+(z&1)*KD (BTRANS), rs=S1+z*384
        mfma3<1, 4, false, true><<<g_pu, blk, 0, stream>>>(
            PRbf, nullptr, nullptr, Kc, KK, Ubf, Dc, KD, 1, Dc, Kc, Kc,
            S1, Kc, nullptr, Cbf, KD);
        // FF1: T1 = tanh([U|C1|C2] @ Wff1)
        mfma3<3, 5, true, false><<<g_ff, blk, 0, stream>>>(
            Ubf, C1bf, C2bf, Dc, 0, Wff1T, 3 * Dc, 0, 0, Dc, 3 * Dc, 768,
            nullptr, 0, PF, nullptr, PFS);
        ep2_k<1><<<(TFF + 255) / 256, blk, 0, stream>>>(PF, PFS, nullptr, nullptr, nullptr,
                                                        nullptr, T1bf, TFF, Dc);
        // FF2: CT = T1 @ Wff2
        mfma3<1, 5, true, false><<<g_ff, blk, 0, stream>>>(
            T1bf, nullptr, nullptr, Dc, 0, Wff2T, Dc, 0, 0, Dc, Dc, 256,
            nullptr, 0, PF, nullptr, PFS);
        ep2_k<2><<<(TFF + 255) / 256, blk, 0, stream>>>(PF, PFS, nullptr, nullptr, nullptr,
                                                        nullptr, CTbf, TFF, Dc);
        // gate
        mfma3<2, 5, true, false><<<g_ff, blk, 0, stream>>>(
            Ubf, CTbf, nullptr, Dc, 0, WgT, 2 * Dc, 0, 0, Dc, 2 * Dc, 512,
            nullptr, 0, PF, nullptr, PFS);
        ep2_k<3><<<(TFF + 255) / 256, blk, 0, stream>>>(PF, PFS, bg, Ubf, CTbf,
                                                        (it == 1) ? out_u : nullptr,
                                                        Ubf, TFF, Dc);
        // next l|r + scorer (residual add)
        mfma3<1, 5, true, false><<<g_lr, blk, 0, stream>>>(
            Ubf, nullptr, nullptr, Dc, 0, WlrT, Dc, 0, 0, 2 * Hc, Dc, 256,
            nullptr, 0, PF, nullptr, TLR);
        ep2_k<6><<<(TLR + 255) / 256, blk, 0, stream>>>(PF, TLR, blr, nullptr, nullptr,
                                                        nullptr, LRMb, TLR, 2 * Hc);
        scorer2_k<true><<<g_sc, blk, 0, stream>>>(LRMb, LRMb + Hc, 2 * Hc, DT,
                                                  span_begin, span_end, Wo, bo, out_sc);
    }

    // out_u written by final ep2<3>. Fill out_all, then scatter.
    copy4_k<<<((Bc * Nc * Dc / 4) + 255) / 256, blk, 0, stream>>>(
        (const float4*)all_span_vecs, (float4*)out_all, Bc * Nc * Dc / 4);
    scatter_k<<<Mrows, blk, 0, stream>>>(out_u, prune_indices, span_lengths, out_all);
}

// Round 12
// 422.573 us; speedup vs baseline: 1.6057x; 1.0034x over previous
//
#include <hip/hip_runtime.h>
#include <math.h>

// Problem constants (match reference)
constexpr int Bc = 2, Kc = 384, Nc = 4096, Dc = 1024;
constexpr int Hc = 150, Lc = 12, DDc = 20, NBc = 10;
constexpr int Mrows = Bc * Kc; // 768

typedef __attribute__((ext_vector_type(8))) unsigned short ushort8;
typedef __attribute__((ext_vector_type(8))) short short8;
typedef __attribute__((ext_vector_type(4))) float f32x4;

__device__ __forceinline__ float sigmoidf_(float x) { return 1.0f / (1.0f + expf(-x)); }

__device__ __forceinline__ unsigned short f2b(float f) {
    unsigned u = __float_as_uint(f);
    unsigned r = (u + 0x7fffu + ((u >> 16) & 1u)) >> 16;
    return (unsigned short)r;
}
__device__ __forceinline__ float b2f(unsigned short u) {
    return __uint_as_float((unsigned)u << 16);
}

__global__ __launch_bounds__(256) void cvt_k(const float* __restrict__ s,
                                             unsigned short* __restrict__ d, int n) {
    for (int i = blockIdx.x * 256 + threadIdx.x; i < n; i += gridDim.x * 256)
        d[i] = f2b(s[i]);
}

// dist table (f32)
__global__ __launch_bounds__(256) void dtab_k(const float* __restrict__ de,
                                              const float* __restrict__ Wd,
                                              const float* __restrict__ bd,
                                              float* __restrict__ dtab) {
    int idx = blockIdx.x * 256 + threadIdx.x;
    if (idx >= NBc * Hc) return;
    int n = idx / Hc, h = idx - n * Hc;
    float s = bd[h];
#pragma unroll
    for (int k = 0; k < DDc; ++k) s = fmaf(de[n * DDc + k], Wd[k * Hc + h], s);
    dtab[n * Hc + h] = s;
}

// f32 W[K][N] -> bf16 WT[N][K]
__global__ __launch_bounds__(256) void trw_k(const float* __restrict__ Wsrc,
                                             unsigned short* __restrict__ WT,
                                             int K, int N) {
    __shared__ unsigned short t[32][33];
    const int k0 = blockIdx.y * 32, n0 = blockIdx.x * 32;
    const int tx = threadIdx.x & 31, ty = threadIdx.x >> 5;
#pragma unroll
    for (int i = 0; i < 4; ++i)
        t[ty + i * 8][tx] = f2b(Wsrc[(size_t)(k0 + ty + i * 8) * N + n0 + tx]);
    __syncthreads();
#pragma unroll
    for (int i = 0; i < 4; ++i)
        WT[(size_t)(n0 + ty + i * 8) * K + k0 + tx] = t[tx][ty + i * 8];
}

// WlrT[r][k], r in [0,320): rows 0..149 = Wl^T, 150..299 = Wr^T, 300..319 = 0
// (zero-padded so global_load_lds staging never reads out of bounds)
__global__ __launch_bounds__(256) void trwlr_k(const float* __restrict__ Wl,
                                               const float* __restrict__ Wr,
                                               const float* __restrict__ bl,
                                               const float* __restrict__ br,
                                               unsigned short* __restrict__ WlrT,
                                               float* __restrict__ blr) {
    int idx = blockIdx.x * 256 + threadIdx.x;
    if (idx < Hc) { blr[idx] = bl[idx]; blr[Hc + idx] = br[idx]; }
    if (idx >= 320 * Dc) return;
    int r = idx >> 10, k = idx & 1023;
    float v = (r < Hc) ? Wl[(size_t)k * Hc + r]
                       : ((r < 2 * Hc) ? Wr[(size_t)k * Hc + (r - Hc)] : 0.0f);
    WlrT[idx] = f2b(v);
}

// bf16 tile transpose: dst[z][C][R] = src[z][R][C]^T
__global__ __launch_bounds__(256) void trb_k(const unsigned short* __restrict__ src,
                                             unsigned short* __restrict__ dst,
                                             int R, int C, long sBatch, long dBatch) {
    __shared__ unsigned short t[32][33];
    const int z = blockIdx.z;
    src += (size_t)z * sBatch;
    dst += (size_t)z * dBatch;
    const int r0 = blockIdx.y * 32, c0 = blockIdx.x * 32;
    const int tx = threadIdx.x & 31, ty = threadIdx.x >> 5;
#pragma unroll
    for (int i = 0; i < 4; ++i)
        t[ty + i * 8][tx] = src[(size_t)(r0 + ty + i * 8) * C + c0 + tx];
    __syncthreads();
#pragma unroll
    for (int i = 0; i < 4; ++i)
        dst[(size_t)(c0 + ty + i * 8) * R + r0 + tx] = t[tx][ty + i * 8];
}

// ---------------------------------------------------------------------------
// mfma3: 64x64 tile, 4 waves x (2x2 16x16 frags), K-step 64, double-buffered.
// GLDS=true (weight GEMMs): global_load_lds width-16 staging into LINEAR
//   [64][64]-short LDS with both-sides XOR swizzle (slot ^= row&7 on the
//   16B-slot index; pre-swizzled global source + swizzled frag read — the
//   same involution, rule #21). No ds_writes, no VGPR round-trip.
// GLDS=false (PU): round-10 reg-staged path (LDA=72 pad; BTRANS supported).
// SPLITK: z = K-chunk, outf += z*oBatch (f32 partials). !SPLITK: z batches.
// EPI: 4 -> outb=bf16(acc*rs[row]) ; 5 -> outf=acc.
// C/D frag layout: row=(lane>>4)*4+reg, col=lane&15 (HW-verified).
// ---------------------------------------------------------------------------
template <int NSRC, int EPI, bool SPLITK, bool BTRANS, bool GLDS>
__global__ __launch_bounds__(256) void mfma3(
    const unsigned short* __restrict__ a0, const unsigned short* __restrict__ a1,
    const unsigned short* __restrict__ a2, int arstride, long aBatch,
    const unsigned short* __restrict__ Bm, int bstride, long wBatch, int wmask,
    int N, int Kd, int chunk,
    const float* __restrict__ rs, long rsBatch,
    float* __restrict__ outf, unsigned short* __restrict__ outb, long oBatch) {
    constexpr int LDA = GLDS ? 64 : 72;
    __shared__ unsigned short Als[2][64 * LDA];
    __shared__ unsigned short Bls[2][64 * LDA];

    const int z = blockIdx.z;
    int kbeg;
    if (SPLITK) {
        kbeg = z * chunk;
        outf += (size_t)z * oBatch;
    } else {
        kbeg = 0;
        chunk = Kd;
        a0 += (size_t)z * aBatch;
        Bm += (size_t)(z & wmask) * wBatch;
        if (rs) rs += (size_t)z * rsBatch;
        if (outb) outb += (size_t)z * oBatch;
    }
    const int kend = kbeg + chunk;

    const int tid = threadIdx.x;
    const int wave = tid >> 6, lane = tid & 63;
    const int wr = wave >> 1, wc = wave & 1;
    const int l15 = lane & 15, lg = lane >> 4;
    const int row0 = blockIdx.y * 64, col0 = blockIdx.x * 64;
    const int srow = tid >> 2, skc = (tid & 3) * 16;

    f32x4 acc[2][2] = {};
    ushort8 ra0, ra1, rb0, rb1;

// ---- GLDS staging: 2 calls/wave for A (8 rows each) + 2 for B ----
#define STAGE_GLDS(b, kb)                                                              \
    {                                                                                  \
        const unsigned short* asrc = a0;                                               \
        int kl0 = (kb);                                                                \
        if (NSRC > 1) {                                                                \
            int s_ = (kb) >> 10;                                                       \
            kl0 = (kb) & 1023;                                                         \
            asrc = (s_ == 0) ? a0 : ((s_ == 1 || NSRC == 2) ? a1 : a2);                \
        }                                                                              \
        _Pragma("unroll") for (int c = 0; c < 2; ++c) {                                \
            int r = wave * 16 + c * 8 + (lane >> 3);                                   \
            int sw = ((lane & 7) ^ (r & 7)) << 3;                                      \
            const unsigned short* ga = asrc + (size_t)(row0 + r) * arstride + kl0 + sw;\
            __builtin_amdgcn_global_load_lds(                                          \
                (const __attribute__((address_space(1))) void*)ga,                     \
                (__attribute__((address_space(3))) void*)&Als[b][(wave * 16 + c * 8) * 64], \
                16, 0, 0);                                                             \
            const unsigned short* gb = Bm + (size_t)(col0 + r) * bstride + (kb) + sw;  \
            __builtin_amdgcn_global_load_lds(                                          \
                (const __attribute__((address_space(1))) void*)gb,                     \
                (__attribute__((address_space(3))) void*)&Bls[b][(wave * 16 + c * 8) * 64], \
                16, 0, 0);                                                             \
        }                                                                              \
    }

#define LOAD_SLAB(kb)                                                                  \
    {                                                                                  \
        int kglob = (kb) + skc;                                                        \
        const unsigned short* asrc = a0;                                               \
        int kl = kglob;                                                                \
        if (NSRC > 1) {                                                                \
            int s = kglob >> 10;                                                       \
            kl = kglob & 1023;                                                         \
            asrc = (s == 0) ? a0 : ((s == 1 || NSRC == 2) ? a1 : a2);                  \
        }                                                                              \
        const unsigned short* p = asrc + (size_t)(row0 + srow) * arstride + kl;        \
        ra0 = *(const ushort8*)p;                                                      \
        ra1 = *(const ushort8*)(p + 8);                                                \
        if (BTRANS) {                                                                  \
            const unsigned short* q = Bm + (size_t)((kb) + srow) * bstride + col0 + skc; \
            rb0 = *(const ushort8*)q;                                                  \
            rb1 = *(const ushort8*)(q + 8);                                            \
        } else {                                                                       \
            int col = col0 + srow;                                                     \
            if (col < N) {                                                             \
                const unsigned short* q = Bm + (size_t)col * bstride + kglob;          \
                rb0 = *(const ushort8*)q;                                              \
                rb1 = *(const ushort8*)(q + 8);                                        \
            } else {                                                                   \
                ushort8 z8 = {};                                                       \
                rb0 = z8;                                                              \
                rb1 = z8;                                                              \
            }                                                                          \
        }                                                                              \
    }

#define WRITE_SLAB(b)                                                                  \
    {                                                                                  \
        *(ushort8*)&Als[b][srow * LDA + skc] = ra0;                                    \
        *(ushort8*)&Als[b][srow * LDA + skc + 8] = ra1;                                \
        if (BTRANS) {                                                                  \
            _Pragma("unroll") for (int j = 0; j < 8; ++j)                              \
                Bls[b][(skc + j) * LDA + srow] = rb0[j];                               \
            _Pragma("unroll") for (int j = 0; j < 8; ++j)                              \
                Bls[b][(skc + 8 + j) * LDA + srow] = rb1[j];                           \
        } else {                                                                       \
            *(ushort8*)&Bls[b][srow * LDA + skc] = rb0;                                \
            *(ushort8*)&Bls[b][srow * LDA + skc + 8] = rb1;                            \
        }                                                                              \
    }

    if (GLDS) {
        STAGE_GLDS(0, kbeg);
    } else {
        LOAD_SLAB(kbeg);
        WRITE_SLAB(0);
    }
    __syncthreads();

    int cur = 0;
    for (int k0 = kbeg; k0 < kend; k0 += 64) {
        const bool more = (k0 + 64 < kend);
        if (more) {
            if (GLDS) STAGE_GLDS(cur ^ 1, k0 + 64)
            else LOAD_SLAB(k0 + 64)
        }
#pragma unroll
        for (int h = 0; h < 2; ++h) {
            short8 af0, af1, bf0, bf1;
            if (GLDS) {
                int sw = (((h * 4 + lg) ^ (l15 & 7)) << 3);
                af0 = *(const short8*)&Als[cur][(wr * 32 + l15) * LDA + sw];
                af1 = *(const short8*)&Als[cur][(wr * 32 + 16 + l15) * LDA + sw];
                bf0 = *(const short8*)&Bls[cur][(wc * 32 + l15) * LDA + sw];
                bf1 = *(const short8*)&Bls[cur][(wc * 32 + 16 + l15) * LDA + sw];
            } else {
                af0 = *(const short8*)&Als[cur][(wr * 32 + l15) * LDA + h * 32 + lg * 8];
                af1 = *(const short8*)&Als[cur][(wr * 32 + 16 + l15) * LDA + h * 32 + lg * 8];
                bf0 = *(const short8*)&Bls[cur][(wc * 32 + l15) * LDA + h * 32 + lg * 8];
                bf1 = *(const short8*)&Bls[cur][(wc * 32 + 16 + l15) * LDA + h * 32 + lg * 8];
            }
            acc[0][0] = __builtin_amdgcn_mfma_f32_16x16x32_bf16(af0, bf0, acc[0][0], 0, 0, 0);
            acc[0][1] = __builtin_amdgcn_mfma_f32_16x16x32_bf16(af0, bf1, acc[0][1], 0, 0, 0);
            acc[1][0] = __builtin_amdgcn_mfma_f32_16x16x32_bf16(af1, bf0, acc[1][0], 0, 0, 0);
            acc[1][1] = __builtin_amdgcn_mfma_f32_16x16x32_bf16(af1, bf1, acc[1][1], 0, 0, 0);
        }
        if (more) {
            int nb = cur ^ 1;
            if (!GLDS) WRITE_SLAB(nb)
            __syncthreads();
            cur = nb;
        }
    }
#undef STAGE_GLDS
#undef LOAD_SLAB
#undef WRITE_SLAB

#pragma unroll
    for (int m = 0; m < 2; ++m)
#pragma unroll
        for (int n = 0; n < 2; ++n)
#pragma unroll
            for (int r = 0; r < 4; ++r) {
                int row = row0 + wr * 32 + m * 16 + lg * 4 + r;
                int col = col0 + wc * 32 + n * 16 + l15;
                if (col >= N) continue;
                size_t ix = (size_t)row * N + col;
                if (EPI == 5) outf[ix] = acc[m][n][r];
                else if (EPI == 4) outb[ix] = f2b(acc[m][n][r] * rs[row]);
            }
}

// ---------------------------------------------------------------------------
// reduce-4-partials + activation
// ---------------------------------------------------------------------------
template <int ACT>
__global__ __launch_bounds__(256) void ep2_k(const float* __restrict__ PF, long pstride,
                                             const float* __restrict__ bias,
                                             const unsigned short* e1,
                                             const unsigned short* e2,
                                             float* outf, unsigned short* outb,
                                             int total, int N) {
    int idx = blockIdx.x * 256 + threadIdx.x;
    if (idx >= total) return;
    float v = PF[idx] + PF[pstride + idx] + PF[2 * pstride + idx] + PF[3 * pstride + idx];
    int col = idx - (idx / N) * N;
    if (ACT == 1) {
        outb[idx] = f2b(tanhf(v));
    } else if (ACT == 2) {
        outb[idx] = f2b(v);
    } else if (ACT == 3) {
        float g = sigmoidf_(v + bias[col]);
        float r = g * b2f(e1[idx]) + (1.0f - g) * b2f(e2[idx]);
        if (outf) outf[idx] = r;
        outb[idx] = f2b(r);
    } else if (ACT == 6) {
        outb[idx] = f2b(v + bias[col]);
    }
}

// ---------------------------------------------------------------------------
// scorer2: MFMA scorer (round-11, verified)
// ---------------------------------------------------------------------------
template <bool ADD>
__global__ __launch_bounds__(256) void scorer2_k(
    const unsigned short* __restrict__ Lm, const unsigned short* __restrict__ Rm,
    int lst, const float* __restrict__ dtab,
    const int* __restrict__ sb, const int* __restrict__ se,
    const float* __restrict__ Wo, const float* __restrict__ bo,
    float* __restrict__ scores) {
    const int b = blockIdx.z;
    const int i0 = blockIdx.y * 16, j0 = blockIdx.x * 16;
    __shared__ unsigned short Lb[16 * 168];
    __shared__ unsigned short Rb[16 * 168];
    __shared__ float Df[10 * 164];
    __shared__ int sbs[16];
    const int tid = threadIdx.x;
    const int wave = tid >> 6, lane = tid & 63;
    const int l15 = lane & 15, lg = lane >> 4;

    for (int idx = tid; idx < 16 * 160; idx += 256) {
        int r = idx / 160, c = idx - r * 160;
        Lb[r * 168 + c] = (c < Hc) ? Lm[(size_t)(b * Kc + i0 + r) * lst + c] : (unsigned short)0;
        Rb[r * 168 + c] = (c < Hc) ? Rm[(size_t)(b * Kc + j0 + r) * lst + c] : (unsigned short)0;
    }
    for (int idx = tid; idx < 10 * 160; idx += 256) {
        int r = idx / 160, c = idx - r * 160;
        Df[r * 164 + c] = (c < Hc) ? dtab[r * Hc + c] : 0.0f;
    }
    if (tid < 16) sbs[tid] = sb[b * Kc + j0 + tid];

    short8 bfr[5];
#pragma unroll
    for (int kc = 0; kc < 5; ++kc) {
#pragma unroll
        for (int j = 0; j < 8; ++j) {
            int k = kc * 32 + lg * 8 + j;
            float v = (k < Hc && l15 < Lc) ? Wo[k * Lc + l15] : 0.0f;
            bfr[kc][j] = f2b(v);
        }
    }
    const int se_i = se[b * Kc + i0 + l15];
    const float bo_l = (l15 < Lc) ? bo[l15] : 0.0f;
    __syncthreads();

#pragma unroll
    for (int t = 0; t < 4; ++t) {
        const int jg = wave * 4 + t;
        int d = sbs[jg] - se_i;
        int da = d < 0 ? -d : d;
        int bucket = (da <= 4) ? da : min(31 - __clz(da) + 3, NBc - 1);
        const float* dp = &Df[bucket * 164];
        f32x4 acc = {};
#pragma unroll
        for (int kc = 0; kc < 5; ++kc) {
            int h0 = kc * 32 + lg * 8;
            ushort8 La = *(const ushort8*)&Lb[l15 * 168 + h0];
            ushort8 Ra = *(const ushort8*)&Rb[jg * 168 + h0];
            f32x4 D0 = *(const f32x4*)&dp[h0];
            f32x4 D1 = *(const f32x4*)&dp[h0 + 4];
            const unsigned* lu = (const unsigned*)&La;
            const unsigned* ru = (const unsigned*)&Ra;
            union { unsigned u[4]; short8 s; } aw;
#pragma unroll
            for (int q = 0; q < 4; ++q) {
                float de0 = (q < 2) ? D0[2 * q] : D1[2 * q - 4];
                float de1 = (q < 2) ? D0[2 * q + 1] : D1[2 * q - 3];
                float lv0 = __uint_as_float(lu[q] << 16);
                float lv1 = __uint_as_float(lu[q] & 0xffff0000u);
                float rv0 = __uint_as_float(ru[q] << 16);
                float rv1 = __uint_as_float(ru[q] & 0xffff0000u);
                float s0 = fmaxf(lv0 + rv0 + de0, 0.0f);
                float s1 = fmaxf(lv1 + rv1 + de1, 0.0f);
                aw.u[q] = (__float_as_uint(s0) >> 16) | (__float_as_uint(s1) & 0xffff0000u);
            }
            acc = __builtin_amdgcn_mfma_f32_16x16x32_bf16(aw.s, bfr[kc], acc, 0, 0, 0);
        }
        if (l15 < Lc) {
#pragma unroll
            for (int r = 0; r < 4; ++r) {
                int irow = lg * 4 + r;
                size_t off = (((size_t)(b * Kc + i0 + irow)) * Kc + (j0 + jg)) * Lc + l15;
                float v = acc[r] + bo_l;
                if (ADD) v += scores[off];
                scores[off] = v;
            }
        }
    }
}

// probs -> PRbf (bf16 only)
__global__ __launch_bounds__(256) void probs_k(const float* __restrict__ scores,
                                               const float* __restrict__ mask,
                                               unsigned short* __restrict__ PRbf) {
    int idx = blockIdx.x * 256 + threadIdx.x;
    if (idx >= Bc * Kc * Kc) return;
    const float* s = scores + (size_t)idx * Lc;
    float m = s[0];
#pragma unroll
    for (int l = 1; l < Lc; ++l) m = fmaxf(m, s[l]);
    PRbf[idx] = f2b(sigmoidf_(m) * mask[idx]);
}

// rowsum over bf16 probs
__global__ __launch_bounds__(256) void rowsum_k(const unsigned short* __restrict__ probs,
                                                float* __restrict__ s1inv) {
    int row = (blockIdx.x * 256 + threadIdx.x) >> 6;
    int lane = threadIdx.x & 63;
    if (row >= Mrows) return;
    const unsigned short* p = probs + (size_t)row * Kc;
    float s = 0.0f;
    for (int j = lane; j < Kc; j += 64) s += b2f(p[j]);
#pragma unroll
    for (int off = 32; off > 0; off >>= 1) s += __shfl_down(s, off);
    if (lane == 0) s1inv[row] = 1.0f / (s + 1e-7f);
}

// colsum over bf16 probs
__global__ __launch_bounds__(256) void colsum_k(const unsigned short* __restrict__ probs,
                                                float* __restrict__ s2inv) {
    int idx = blockIdx.x * 256 + threadIdx.x;
    if (idx >= Mrows) return;
    int b = idx / Kc, j = idx - b * Kc;
    const unsigned short* p = probs + (size_t)b * Kc * Kc + j;
    float s = 0.0f;
    for (int i = 0; i < Kc; ++i) s += b2f(p[(size_t)i * Kc]);
    s2inv[idx] = 1.0f / (s + 1e-7f);
}

__global__ __launch_bounds__(256) void copy4_k(const float4* __restrict__ s,
                                               float4* __restrict__ d, int n4) {
    int i = blockIdx.x * 256 + threadIdx.x;
    if (i < n4) d[i] = s[i];
}

// scatter: numpy sequential-set semantics
__global__ __launch_bounds__(256) void scatter_k(const float* __restrict__ Uf,
                                                 const int* __restrict__ pidx,
                                                 const int* __restrict__ slen,
                                                 float* __restrict__ out_all) {
    int bk = blockIdx.x;
    int b = bk / Kc, k = bk - b * Kc;
    if (k >= slen[b]) return;
    int idx = pidx[bk];
    if (k + 1 < Kc && pidx[bk + 1] == idx) return;
    const float4* s = (const float4*)(Uf + (size_t)bk * Dc);
    float4* d = (float4*)(out_all + ((size_t)b * Nc + idx) * Dc);
    for (int c = threadIdx.x; c < Dc / 4; c += 256) d[c] = s[c];
}

// ---------------------------------------------------------------------------
extern "C" void kernel_launch(void* const* d_in, const int* in_sizes, int n_in,
                              void* d_out, int out_size, void* d_ws, size_t ws_size,
                              hipStream_t stream) {
    const float* span_vecs = (const float*)d_in[0];
    const float* all_span_vecs = (const float*)d_in[1];
    const int* span_begin = (const int*)d_in[2];
    const int* span_end = (const int*)d_in[3];
    const float* square_mask = (const float*)d_in[4];
    const int* prune_indices = (const int*)d_in[5];
    const int* span_lengths = (const int*)d_in[6];
    const float* Wl = (const float*)d_in[8];
    const float* bl = (const float*)d_in[9];
    const float* Wr = (const float*)d_in[10];
    const float* br = (const float*)d_in[11];
    const float* dist_emb = (const float*)d_in[12];
    const float* Wd = (const float*)d_in[13];
    const float* bd = (const float*)d_in[14];
    const float* Wo = (const float*)d_in[15];
    const float* bo = (const float*)d_in[16];
    const float* Wff1 = (const float*)d_in[17];
    const float* Wff2 = (const float*)d_in[18];
    const float* Wg = (const float*)d_in[19];
    const float* bg = (const float*)d_in[20];

    float* out_all = (float*)d_out;                    // B*N*D = 8,388,608 floats
    float* out_u = out_all + (size_t)Bc * Nc * Dc;     // B*K*D
    float* out_sc = out_u + (size_t)Mrows * Dc;        // B*K*K*L

    // Scratch in out_all (dead until final copy). Offsets (floats), 64-aligned.
    float* w = out_all;
    float* DT = w;                                          // 1,600
    float* S1 = w + 1600;                                   // [4][384] f32
    unsigned short* LRMb = (unsigned short*)(w + 3136);     // [768][300] bf16
    unsigned short* Ubf = (unsigned short*)(w + 118336);    // [768][1024] bf16
    unsigned short* Cbf = (unsigned short*)(w + 511552);    // [4][384][1024] bf16
    unsigned short* T1bf = (unsigned short*)(w + 1297984);  // 786,432 sh
    unsigned short* PRbf = (unsigned short*)(w + 1494592);  // [4][384][384] bf16
    float* PF = w + 1789504;                                // [4][768][1024] f32
    unsigned short* Wff1T = (unsigned short*)(w + 4935232); // [1024][3072]
    unsigned short* Wff2T = (unsigned short*)(w + 6508096); // [1024][1024]
    unsigned short* WgT = (unsigned short*)(w + 7032384);   // [1024][2048]
    unsigned short* WlrT = (unsigned short*)(w + 8080960);  // [320][1024] (zero-padded)
    float* blr = w + 8244800;                               // 320 -> end 8,245,120
    const long KK = (long)Kc * Kc;   // 147,456
    const long KD = (long)Kc * Dc;   // 393,216
    unsigned short* C1bf = Cbf;
    unsigned short* C2bf = Cbf + 2 * KD;
    unsigned short* PT = PRbf + 2 * KK;
    unsigned short* CTbf = C1bf;                 // alias: C1 dead after FF1
    const long PFS = (long)Mrows * Dc;           // 786,432

    dim3 blk(256);
    dim3 g_sc(Kc / 16, Kc / 16, Bc);
    dim3 g_ff(16, 12, 4);
    dim3 g_lr(5, 12, 4);
    dim3 g_pu(16, 6, 4);
    dim3 g_trp(12, 12, 2);

    // one-time conversions
    cvt_k<<<2048, blk, 0, stream>>>(span_vecs, Ubf, Mrows * Dc);
    trw_k<<<dim3(32, 96), blk, 0, stream>>>(Wff1, Wff1T, 3 * Dc, Dc);
    trw_k<<<dim3(32, 32), blk, 0, stream>>>(Wff2, Wff2T, Dc, Dc);
    trw_k<<<dim3(32, 64), blk, 0, stream>>>(Wg, WgT, 2 * Dc, Dc);
    trwlr_k<<<(320 * Dc + 255) / 256, blk, 0, stream>>>(Wl, Wr, bl, br, WlrT, blr);
    dtab_k<<<(NBc * Hc + 255) / 256, blk, 0, stream>>>(dist_emb, Wd, bd, DT);

    const int TFF = Mrows * Dc;       // 786,432
    const int TLR = Mrows * 2 * Hc;   // 230,400

    // initial l|r projection + scorer
    mfma3<1, 5, true, false, true><<<g_lr, blk, 0, stream>>>(
        Ubf, nullptr, nullptr, Dc, 0, WlrT, Dc, 0, 0, 2 * Hc, Dc, 256,
        nullptr, 0, PF, nullptr, TLR);
    ep2_k<6><<<(TLR + 255) / 256, blk, 0, stream>>>(PF, TLR, blr, nullptr, nullptr,
                                                    nullptr, LRMb, TLR, 2 * Hc);
    scorer2_k<false><<<g_sc, blk, 0, stream>>>(LRMb, LRMb + Hc, 2 * Hc, DT,
                                               span_begin, span_end, Wo, bo, out_sc);

    for (int it = 0; it < 2; ++it) {
        probs_k<<<(Bc * Kc * Kc + 255) / 256, blk, 0, stream>>>(out_sc, square_mask, PRbf);
        rowsum_k<<<Mrows / 4, blk, 0, stream>>>(PRbf, S1);
        colsum_k<<<(Mrows + 255) / 256, blk, 0, stream>>>(PRbf, S1 + Mrows);
        trb_k<<<g_trp, blk, 0, stream>>>(PRbf, PT, Kc, Kc, KK, KK);
        // fused PU: A=PRbf+z*KK, B=Ubf+(z&1)*KD (BTRANS reg-staged), rs=S1+z*384
        mfma3<1, 4, false, true, false><<<g_pu, blk, 0, stream>>>(
            PRbf, nullptr, nullptr, Kc, KK, Ubf, Dc, KD, 1, Dc, Kc, Kc,
            S1, Kc, nullptr, Cbf, KD);
        // FF1: T1 = tanh([U|C1|C2] @ Wff1)
        mfma3<3, 5, true, false, true><<<g_ff, blk, 0, stream>>>(
            Ubf, C1bf, C2bf, Dc, 0, Wff1T, 3 * Dc, 0, 0, Dc, 3 * Dc, 768,
            nullptr, 0, PF, nullptr, PFS);
        ep2_k<1><<<(TFF + 255) / 256, blk, 0, stream>>>(PF, PFS, nullptr, nullptr, nullptr,
                                                        nullptr, T1bf, TFF, Dc);
        // FF2: CT = T1 @ Wff2
        mfma3<1, 5, true, false, true><<<g_ff, blk, 0, stream>>>(
            T1bf, nullptr, nullptr, Dc, 0, Wff2T, Dc, 0, 0, Dc, Dc, 256,
            nullptr, 0, PF, nullptr, PFS);
        ep2_k<2><<<(TFF + 255) / 256, blk, 0, stream>>>(PF, PFS, nullptr, nullptr, nullptr,
                                                        nullptr, CTbf, TFF, Dc);
        // gate
        mfma3<2, 5, true, false, true><<<g_ff, blk, 0, stream>>>(
            Ubf, CTbf, nullptr, Dc, 0, WgT, 2 * Dc, 0, 0, Dc, 2 * Dc, 512,
            nullptr, 0, PF, nullptr, PFS);
        ep2_k<3><<<(TFF + 255) / 256, blk, 0, stream>>>(PF, PFS, bg, Ubf, CTbf,
                                                        (it == 1) ? out_u : nullptr,
                                                        Ubf, TFF, Dc);
        // next l|r + scorer (residual add)
        mfma3<1, 5, true, false, true><<<g_lr, blk, 0, stream>>>(
            Ubf, nullptr, nullptr, Dc, 0, WlrT, Dc, 0, 0, 2 * Hc, Dc, 256,
            nullptr, 0, PF, nullptr, TLR);
        ep2_k<6><<<(TLR + 255) / 256, blk, 0, stream>>>(PF, TLR, blr, nullptr, nullptr,
                                                        nullptr, LRMb, TLR, 2 * Hc);
        scorer2_k<true><<<g_sc, blk, 0, stream>>>(LRMb, LRMb + Hc, 2 * Hc, DT,
                                                  span_begin, span_end, Wo, bo, out_sc);
    }

    // out_u written by final ep2<3>. Fill out_all, then scatter.
    copy4_k<<<((Bc * Nc * Dc / 4) + 255) / 256, blk, 0, stream>>>(
        (const float4*)all_span_vecs, (float4*)out_all, Bc * Nc * Dc / 4);
    scatter_k<<<Mrows, blk, 0, stream>>>(out_u, prune_indices, span_lengths, out_all);
}